// Round 14
// baseline (315.631 us; speedup 1.0000x reference)
//
#include <hip/hip_runtime.h>
#include <math.h>

// Problem constants (fixed by the reference)
#define G    120     // B*T frames
#define Nn   2000    // nodes per frame
#define Ee   32000   // edges per frame
#define Tt   30
#define Bb   4
#define Fg   128     // GRU hidden
#define QCAP 9216    // CSR capacity per (frame,quadrant); expected 8000, sigma 78
#define TSLOT 48     // transposed-ELL slots/node: slot0=self + up to 47 edges

static __device__ __forceinline__ unsigned short f2bf(float f) {
    unsigned u = __float_as_uint(f);
    u += 0x7fffu + ((u >> 16) & 1u);          // round-to-nearest-even
    return (unsigned short)(u >> 16);
}

// ---------------- fp8 e4m3 encode/decode: HW builtins if available, SW fallback.
#if defined(__has_builtin)
#if __has_builtin(__builtin_amdgcn_cvt_f32_fp8) && __has_builtin(__builtin_amdgcn_cvt_pk_fp8_f32)
#define HW_FP8 1
#endif
#if __has_builtin(__builtin_amdgcn_cvt_pk_f32_fp8)
#define HW_FP8_PK 1
typedef float floatx2 __attribute__((ext_vector_type(2)));
#endif
#endif

static __device__ __forceinline__ unsigned fp8_enc_sw(float x) {
    unsigned s = (__float_as_uint(x) >> 24) & 0x80u;
    float ax = fminf(fabsf(x), 448.f);
    unsigned em;
    if (ax < 0.015625f) {
        em = (unsigned)__float2int_rn(ax * 512.f);
    } else {
        int e = (int)(__float_as_uint(ax) >> 23) - 127;
        float r = ax * __uint_as_float((unsigned)((130 - e) << 23));
        int q = __float2int_rn(r);
        em = (unsigned)(((e + 7) << 3) + (q - 8));
        em = min(em, 126u);
    }
    return s | em;
}
static __device__ __forceinline__ float fp8_dec_sw(unsigned b) {
    unsigned em = b & 0x7fu;
    float mag;
    if (em < 8u) mag = (float)em * 0.001953125f;
    else mag = __uint_as_float((((em >> 3) + 120u) << 23) | ((em & 7u) << 20));
    return (b & 0x80u) ? -mag : mag;
}
static __device__ __forceinline__ unsigned fp8_pack4(float a, float b, float c, float d) {
#ifdef HW_FP8
    int w = __builtin_amdgcn_cvt_pk_fp8_f32(a, b, 0, false);
    w = __builtin_amdgcn_cvt_pk_fp8_f32(c, d, w, true);
    return (unsigned)w;
#else
    return fp8_enc_sw(a) | (fp8_enc_sw(b) << 8) | (fp8_enc_sw(c) << 16) | (fp8_enc_sw(d) << 24);
#endif
}
static __device__ __forceinline__ void fp8x4_dec(unsigned dw, float* o) {
#ifdef HW_FP8_PK
    floatx2 lo = __builtin_amdgcn_cvt_pk_f32_fp8((int)dw, false);
    floatx2 hi = __builtin_amdgcn_cvt_pk_f32_fp8((int)dw, true);
    o[0] = lo[0]; o[1] = lo[1]; o[2] = hi[0]; o[3] = hi[1];
#else
    o[0] = fp8_dec_sw(dw & 0xffu);
    o[1] = fp8_dec_sw((dw >> 8) & 0xffu);
    o[2] = fp8_dec_sw((dw >> 16) & 0xffu);
    o[3] = fp8_dec_sw((dw >> 24) & 0xffu);
#endif
}

// ---- K1: fused build + per-quadrant degree counting-sort.
// Emits: dis/startA/cntA (by node, for overflow), sorted-column ellT, cntS/ordS
// (by sorted position), csr (global, only if overflow), emb zeroed.
__global__ void __launch_bounds__(1024, 1)
k_build(const int* __restrict__ ei, float* __restrict__ dis,
        int* __restrict__ startA, int* __restrict__ cntA,
        int* __restrict__ csr, unsigned* __restrict__ ellT,
        int* __restrict__ cntS, int* __restrict__ ordS,
        float* __restrict__ emb) {
    __shared__ int   hist[Nn];        // counts, then own-quadrant cursor
    __shared__ float disl[Nn];
    __shared__ int   ws[512];
    __shared__ int   csr_l[QCAP];
    __shared__ int   cntQ[500];
    __shared__ int   exQ[500];
    __shared__ int   nodeAt[500];     // sorted position -> local node idx
    __shared__ int   dh[64];          // degree histogram, then cursor
    __shared__ int   db[64];          // degree-bin exclusive base
    __shared__ int   ovfS;
    int i = blockIdx.x;               // 0..479
    int xcd = i & 7;
    int j = i >> 3;                   // 0..59
    int f15 = j >> 2;                 // 0..14
    int q = j & 3;
    int g = xcd * 15 + f15;
    int gq = g * 4 + q;
    int lo = q * 500;
    int tid = threadIdx.x;
    // P1: init
    for (int idx = tid; idx < Nn; idx += 1024) hist[idx] = 0;
    if (tid < 64) dh[tid] = 0;
    if (tid == 0) ovfS = 0;
    if (q == 0 && tid < 64) emb[g * 64 + tid] = 0.f;
    __syncthreads();
    // P2: full-frame histogram of destinations
    const int* srcp = ei + (size_t)g * 2 * Ee;
    const int* dstp = srcp + Ee;
    for (int it = tid; it < Ee / 4; it += 1024) {
        int4 d = reinterpret_cast<const int4*>(dstp)[it];
        atomicAdd(&hist[d.x], 1);
        atomicAdd(&hist[d.y], 1);
        atomicAdd(&hist[d.z], 1);
        atomicAdd(&hist[d.w], 1);
    }
    __syncthreads();
    // P3a: dis for all nodes; own-quadrant counts for scan
    for (int idx = tid; idx < Nn; idx += 1024) disl[idx] = rsqrtf((float)hist[idx] + 1.0f);
    int cnt = 0;
    if (tid < 512) ws[tid] = (tid < 500) ? hist[lo + tid] : 0;
    if (tid < 500) cnt = hist[lo + tid];
    __syncthreads();
    // P3b: inclusive scan over 512
    for (int off = 1; off < 512; off <<= 1) {
        int v = 0;
        if (tid < 512 && tid >= off) v = ws[tid - off];
        __syncthreads();
        if (tid < 512) ws[tid] += v;
        __syncthreads();
    }
    int ex = 0;
    if (tid < 500) ex = ws[tid] - cnt;
    // P3c: cursor + per-node arrays + degree histogram
    if (tid < 500) {
        hist[lo + tid] = ex;                       // cursor for P4
        cntQ[tid] = cnt;
        exQ[tid] = ex;
        if (cnt > TSLOT - 1) atomicMax(&ovfS, 1);
        atomicAdd(&dh[min(cnt, 63)], 1);
    }
    __syncthreads();
    // P3d: exclusive scan of degree bins (serial, 64 elems), then cursor=base
    if (tid == 0) {
        int s = 0;
        for (int b = 0; b < 64; ++b) { db[b] = s; s += dh[b]; }
    }
    __syncthreads();
    if (tid < 64) dh[tid] = db[tid];               // cursor per bin
    __syncthreads();
    // P3e: assign sorted positions
    if (tid < 500) {
        int p = atomicAdd(&dh[min(cnt, 63)], 1);
        nodeAt[p] = tid;
    }
    // P4: fill own-quadrant CSR in LDS
    for (int it = tid; it < Ee / 4; it += 1024) {
        int4 d = reinterpret_cast<const int4*>(dstp)[it];
        int4 s = reinterpret_cast<const int4*>(srcp)[it];
        if (d.x >= lo && d.x < lo + 500) { int p = atomicAdd(&hist[d.x], 1); if (p < QCAP) csr_l[p] = s.x; }
        if (d.y >= lo && d.y < lo + 500) { int p = atomicAdd(&hist[d.y], 1); if (p < QCAP) csr_l[p] = s.y; }
        if (d.z >= lo && d.z < lo + 500) { int p = atomicAdd(&hist[d.z], 1); if (p < QCAP) csr_l[p] = s.z; }
        if (d.w >= lo && d.w < lo + 500) { int p = atomicAdd(&hist[d.w], 1); if (p < QCAP) csr_l[p] = s.w; }
    }
    __syncthreads();
    // P5: per-node outputs. Thread t emits SORTED position t (node nodeAt[t]):
    // ELL stores coalesced across t; loop trip wave-uniform (sorted degrees).
    if (tid < 500) {
        // by-node arrays (overflow fallback + dis)
        int n_own = lo + tid;
        size_t gn_own = (size_t)g * Nn + n_own;
        cntA[gn_own] = cnt;
        startA[gn_own] = gq * QCAP + ex;
        dis[gn_own] = disl[n_own];
        // sorted emit
        int sl = nodeAt[tid];                      // local node idx at position tid
        int n2 = lo + sl;
        int cnt2 = cntQ[sl];
        int ex2 = exQ[sl];
        int c = q * 500 + tid;                     // frame-global sorted column
        size_t gc = (size_t)g * Nn + c;
        cntS[gc] = cnt2;
        ordS[gc] = n2;
        float dn2 = disl[n2];
        unsigned* et = ellT + (size_t)g * TSLOT * Nn + c;
        et[0] = (unsigned)n2 | ((unsigned)f2bf(dn2 * dn2) << 16);
        int m2 = min(cnt2, TSLOT - 1);
        for (int e = 0; e < m2; ++e) {
            int s = csr_l[ex2 + e];
            et[(size_t)(e + 1) * Nn] = (unsigned)s | ((unsigned)f2bf(disl[s] * dn2) << 16);
        }
    }
    __syncthreads();
    // P6: global CSR write only if some node overflowed (exact fallback path)
    if (ovfS) {
        int total = ws[511];
        int* cg = csr + (size_t)gq * QCAP;
        for (int it = tid; it < total; it += 1024) cg[it] = csr_l[it];
    }
}

// ---- K2: fully-fused per-lane pipeline: aggX (sorted-ELL gather of x, regs)
// -> h1 = relu(aggX@W1+b1) in regs -> t2 = h1@W2 in regs -> fp8 store by node.
// W1/W2/biases read via uniform scalar loads (no per-lane LDS traffic).
__global__ void __launch_bounds__(256)
k_fused(const float* __restrict__ x, const unsigned* __restrict__ ellT,
        const int* __restrict__ cntS, const int* __restrict__ ordS,
        const int* __restrict__ startA, const int* __restrict__ csr,
        const float* __restrict__ dis,
        const float* __restrict__ W1, const float* __restrict__ b1,
        const float* __restrict__ W2, unsigned char* __restrict__ t2f) {
    int i = blockIdx.x;                 // 960 = 8 xcd * 15 frames * 8 pos-blocks
    int xcd = i & 7;
    int j = i >> 3;                     // 0..119
    int g = xcd * 15 + (j >> 3);
    int blk = j & 7;
    int p = blk * 256 + threadIdx.x;    // sorted position
    bool valid = (p < Nn);
    size_t gp = (size_t)g * Nn + (valid ? p : 0);
    int n = valid ? ordS[gp] : 0;
    int cnt = valid ? cntS[gp] : 0;
    int myc = valid ? (min(cnt, TSLOT - 1) + 1) : 0;
    // phase 0: aggregate raw x (8-dim) into registers via sorted ELL
    float aX[8];
#pragma unroll
    for (int k = 0; k < 8; ++k) aX[k] = 0.f;
    {
        const unsigned* et = ellT + (size_t)g * TSLOT * Nn + (valid ? p : 0);
        const float4* x4 = reinterpret_cast<const float4*>(x + (size_t)g * Nn * 8);
        for (int e = 0; e < TSLOT; ++e) {
            if (!__any(e < myc)) break;
            if (e < myc) {
                unsigned u = et[(size_t)e * Nn];
                float w = __uint_as_float(u & 0xffff0000u);
                int s = u & 0xffffu;
                float4 r0 = x4[s * 2], r1 = x4[s * 2 + 1];
                aX[0] += r0.x * w; aX[1] += r0.y * w; aX[2] += r0.z * w; aX[3] += r0.w * w;
                aX[4] += r1.x * w; aX[5] += r1.y * w; aX[6] += r1.z * w; aX[7] += r1.w * w;
            }
        }
        if (cnt > TSLOT - 1) {          // rare overflow (deg > 47)
            size_t gn = (size_t)g * Nn + n;
            float dn = dis[gn];
            int start = startA[gn];
            const float* dsg = dis + (size_t)g * Nn;
            for (int e = TSLOT - 1; e < cnt; ++e) {
                int s = csr[start + e];
                float w = dsg[s] * dn;
                float4 r0 = x4[s * 2], r1 = x4[s * 2 + 1];
                aX[0] += r0.x * w; aX[1] += r0.y * w; aX[2] += r0.z * w; aX[3] += r0.w * w;
                aX[4] += r1.x * w; aX[5] += r1.y * w; aX[6] += r1.z * w; aX[7] += r1.w * w;
            }
        }
    }
    // phase 1: h1 = relu(aX @ W1 + b1), W1/b1 uniform scalar loads
    float h1r[64];
    {
        const float4* b14 = reinterpret_cast<const float4*>(b1);
#pragma unroll
        for (int f4 = 0; f4 < 16; ++f4) {
            float4 b = b14[f4];
            h1r[4 * f4 + 0] = b.x; h1r[4 * f4 + 1] = b.y;
            h1r[4 * f4 + 2] = b.z; h1r[4 * f4 + 3] = b.w;
        }
        const float4* W14 = reinterpret_cast<const float4*>(W1);
#pragma unroll
        for (int k = 0; k < 8; ++k) {
            float hk = aX[k];
#pragma unroll
            for (int f4 = 0; f4 < 16; ++f4) {
                float4 w = W14[k * 16 + f4];
                h1r[4 * f4 + 0] += hk * w.x; h1r[4 * f4 + 1] += hk * w.y;
                h1r[4 * f4 + 2] += hk * w.z; h1r[4 * f4 + 3] += hk * w.w;
            }
        }
#pragma unroll
        for (int f = 0; f < 64; ++f) h1r[f] = fmaxf(h1r[f], 0.f);
    }
    // phase 2: t2 = h1 @ W2 (fp8 out), W2 uniform scalar loads
    float acc2[64];
#pragma unroll
    for (int f = 0; f < 64; ++f) acc2[f] = 0.f;
    {
        const float4* W24 = reinterpret_cast<const float4*>(W2);
#pragma unroll 4
        for (int k = 0; k < 64; ++k) {
            float hk = h1r[k];
#pragma unroll
            for (int f4 = 0; f4 < 16; ++f4) {
                float4 w = W24[k * 16 + f4];
                acc2[4 * f4 + 0] += hk * w.x; acc2[4 * f4 + 1] += hk * w.y;
                acc2[4 * f4 + 2] += hk * w.z; acc2[4 * f4 + 3] += hk * w.w;
            }
        }
    }
    if (valid) {
        uint4 o0, o1, o2, o3;
        o0.x = fp8_pack4(acc2[0],  acc2[1],  acc2[2],  acc2[3]);
        o0.y = fp8_pack4(acc2[4],  acc2[5],  acc2[6],  acc2[7]);
        o0.z = fp8_pack4(acc2[8],  acc2[9],  acc2[10], acc2[11]);
        o0.w = fp8_pack4(acc2[12], acc2[13], acc2[14], acc2[15]);
        o1.x = fp8_pack4(acc2[16], acc2[17], acc2[18], acc2[19]);
        o1.y = fp8_pack4(acc2[20], acc2[21], acc2[22], acc2[23]);
        o1.z = fp8_pack4(acc2[24], acc2[25], acc2[26], acc2[27]);
        o1.w = fp8_pack4(acc2[28], acc2[29], acc2[30], acc2[31]);
        o2.x = fp8_pack4(acc2[32], acc2[33], acc2[34], acc2[35]);
        o2.y = fp8_pack4(acc2[36], acc2[37], acc2[38], acc2[39]);
        o2.z = fp8_pack4(acc2[40], acc2[41], acc2[42], acc2[43]);
        o2.w = fp8_pack4(acc2[44], acc2[45], acc2[46], acc2[47]);
        o3.x = fp8_pack4(acc2[48], acc2[49], acc2[50], acc2[51]);
        o3.y = fp8_pack4(acc2[52], acc2[53], acc2[54], acc2[55]);
        o3.z = fp8_pack4(acc2[56], acc2[57], acc2[58], acc2[59]);
        o3.w = fp8_pack4(acc2[60], acc2[61], acc2[62], acc2[63]);
        uint4* op = reinterpret_cast<uint4*>(t2f + ((size_t)g * Nn + n) * 64);
        op[0] = o0; op[1] = o1; op[2] = o2; op[3] = o3;
    }
}

// ---- K3: sorted node-per-lane aggregation of t2 (fp8) + relu + mean-pool,
// feature-split: 512 thr = 8 waves; wave = 64 sorted positions x 32 features.
__global__ void __launch_bounds__(512)
k_agg64R3(const unsigned char* __restrict__ t2f, const unsigned* __restrict__ ellT,
          const int* __restrict__ cntS, const int* __restrict__ ordS,
          const int* __restrict__ startA, const int* __restrict__ csr,
          const float* __restrict__ dis, const float* __restrict__ bias,
          float* __restrict__ emb) {
    int i = blockIdx.x;                 // 960 = 8 xcd * 15 frames * 8 pos-blocks
    int xcd = i & 7;
    int j = i >> 3;                     // 0..119
    int g = xcd * 15 + (j >> 3);
    int blk = j & 7;
    int tid = threadIdx.x;              // 0..511
    int w = tid >> 6;                   // wave 0..7
    int lane = tid & 63;
    int ng = w >> 1;                    // position group 0..3
    int half = w & 1;                   // feature half
    int p = blk * 256 + ng * 64 + lane; // sorted position
    bool valid = (p < Nn);
    size_t gp = (size_t)g * Nn + (valid ? p : 0);
    int cnt = valid ? cntS[gp] : 0;
    int myc = valid ? (min(cnt, TSLOT - 1) + 1) : 0;
    float acc[32];
#pragma unroll
    for (int k = 0; k < 32; ++k) acc[k] = 0.f;
    const unsigned* et = ellT + (size_t)g * TSLOT * Nn + (valid ? p : 0);
    const uint4* t2g = reinterpret_cast<const uint4*>(t2f + (size_t)g * Nn * 64);
#define ROWFMA(dw, base) { float o_[4]; fp8x4_dec(dw, o_); \
    acc[base + 0] += o_[0] * wt; acc[base + 1] += o_[1] * wt; \
    acc[base + 2] += o_[2] * wt; acc[base + 3] += o_[3] * wt; }
    for (int e = 0; e < TSLOT; ++e) {
        if (!__any(e < myc)) break;
        if (e < myc) {
            unsigned u = et[(size_t)e * Nn];
            float wt = __uint_as_float(u & 0xffff0000u);
            int s = u & 0xffffu;
            const uint4* row = t2g + s * 4 + half * 2;
            uint4 r0 = row[0], r1 = row[1];
            ROWFMA(r0.x, 0)  ROWFMA(r0.y, 4)  ROWFMA(r0.z, 8)  ROWFMA(r0.w, 12)
            ROWFMA(r1.x, 16) ROWFMA(r1.y, 20) ROWFMA(r1.z, 24) ROWFMA(r1.w, 28)
        }
    }
    if (cnt > TSLOT - 1) {              // rare overflow (deg > 47)
        int n = ordS[gp];
        size_t gn = (size_t)g * Nn + n;
        float dn = dis[gn];
        int start = startA[gn];
        const float* dsg = dis + (size_t)g * Nn;
        for (int e = TSLOT - 1; e < cnt; ++e) {
            int s = csr[start + e];
            float wt = dsg[s] * dn;
            const uint4* row = t2g + s * 4 + half * 2;
            uint4 r0 = row[0], r1 = row[1];
            ROWFMA(r0.x, 0)  ROWFMA(r0.y, 4)  ROWFMA(r0.z, 8)  ROWFMA(r0.w, 12)
            ROWFMA(r1.x, 16) ROWFMA(r1.y, 20) ROWFMA(r1.z, 24) ROWFMA(r1.w, 28)
        }
    }
#undef ROWFMA
    // bias + relu + wave-pool (butterfly per feature), then 1 atomic per lane
    float mypool = 0.f;
#pragma unroll
    for (int k = 0; k < 32; ++k) {
        float v = valid ? fmaxf(acc[k] + bias[half * 32 + k], 0.f) : 0.f;
        v += __shfl_xor(v, 1);  v += __shfl_xor(v, 2);  v += __shfl_xor(v, 4);
        v += __shfl_xor(v, 8);  v += __shfl_xor(v, 16); v += __shfl_xor(v, 32);
        if (lane == k) mypool = v;
    }
    if (lane < 32) atomicAdd(&emb[g * 64 + half * 32 + lane], mypool * (1.0f / Nn));
}

// ---- K4: gi[g][384] = emb[g] @ W_ih^T + b_ih (parallel over frames)
__global__ void k_gi(const float* __restrict__ emb, const float* __restrict__ W_ih,
                     const float* __restrict__ b_ih, float* __restrict__ gi) {
    __shared__ float xs[64];
    int g = blockIdx.x;          // g = b*Tt + t
    int j = threadIdx.x;         // 0..383
    if (j < 64) xs[j] = emb[g * 64 + j];
    __syncthreads();
    float a0 = 0.f, a1 = 0.f, a2 = 0.f, a3 = 0.f;
    const float* wr = W_ih + j * 64;
#pragma unroll
    for (int k = 0; k < 16; ++k) {
        a0 += wr[4 * k + 0] * xs[4 * k + 0];
        a1 += wr[4 * k + 1] * xs[4 * k + 1];
        a2 += wr[4 * k + 2] * xs[4 * k + 2];
        a3 += wr[4 * k + 3] * xs[4 * k + 3];
    }
    gi[(size_t)g * 384 + j] = b_ih[j] + ((a0 + a1) + (a2 + a3));
}

// ---- K5: sequential GRU over T, one block per batch, W_hh in regs + final FC
__global__ void __launch_bounds__(768, 1)
k_gru_seq(const float* __restrict__ gi, const float* __restrict__ W_hh,
          const float* __restrict__ b_hh, const float* __restrict__ fc_w,
          const float* __restrict__ fc_b, float* __restrict__ out) {
    __shared__ float h[Fg];
    __shared__ float part[768];
    int b = blockIdx.x;                  // batch
    int tid = threadIdx.x;               // 0..767
    int row = tid >> 1;                  // gate-row 0..383
    int half = tid & 1;                  // which 64-slice of k
    float w[64];
    const float* wr = W_hh + (size_t)row * Fg + half * 64;
#pragma unroll
    for (int i = 0; i < 64; ++i) w[i] = wr[i];
    if (tid < Fg) h[tid] = 0.f;
    __syncthreads();
    for (int t = 0; t < Tt; ++t) {
        const float* hh = &h[half * 64];
        float a0 = 0.f, a1 = 0.f, a2 = 0.f, a3 = 0.f;
#pragma unroll
        for (int i = 0; i < 16; ++i) {
            a0 += w[4 * i + 0] * hh[4 * i + 0];
            a1 += w[4 * i + 1] * hh[4 * i + 1];
            a2 += w[4 * i + 2] * hh[4 * i + 2];
            a3 += w[4 * i + 3] * hh[4 * i + 3];
        }
        part[tid] = (a0 + a1) + (a2 + a3);
        __syncthreads();
        if (tid < Fg) {
            int j = tid;
            const float* gib = gi + ((size_t)b * Tt + t) * 384;
            float hr = b_hh[j]       + part[2 * j]           + part[2 * j + 1];
            float hz = b_hh[128 + j] + part[2 * (128 + j)]   + part[2 * (128 + j) + 1];
            float hn = b_hh[256 + j] + part[2 * (256 + j)]   + part[2 * (256 + j) + 1];
            float r  = 1.f / (1.f + expf(-(gib[j] + hr)));
            float z  = 1.f / (1.f + expf(-(gib[128 + j] + hz)));
            float nn = tanhf(gib[256 + j] + r * hn);
            h[j] = (1.f - z) * nn + z * h[j];
        }
        __syncthreads();
    }
    if (tid < 2) {
        float acc = fc_b[tid];
        for (int k = 0; k < Fg; ++k) acc += fc_w[tid * Fg + k] * h[k];
        out[b * 2 + tid] = acc;
    }
}

// ----------------------------------------------------------------- launcher
extern "C" void kernel_launch(void* const* d_in, const int* in_sizes, int n_in,
                              void* d_out, int out_size, void* d_ws, size_t ws_size,
                              hipStream_t stream) {
    const float* x     = (const float*)d_in[0];
    const int*   ei    = (const int*)  d_in[1];
    const float* W1    = (const float*)d_in[2];
    const float* b1    = (const float*)d_in[3];
    const float* W2    = (const float*)d_in[4];
    const float* b2    = (const float*)d_in[5];
    const float* W_ih  = (const float*)d_in[6];
    const float* W_hh  = (const float*)d_in[7];
    const float* b_ih  = (const float*)d_in[8];
    const float* b_hh  = (const float*)d_in[9];
    const float* fc_w  = (const float*)d_in[10];
    const float* fc_b  = (const float*)d_in[11];
    float* out = (float*)d_out;

    char* ws = (char*)d_ws;
    size_t off = 0;
    auto alloc = [&](size_t bytes) -> void* {
        void* p = ws + off;
        off = (off + bytes + 255) & ~(size_t)255;
        return p;
    };
    float*    dis    = (float*)   alloc((size_t)G * Nn * 4);
    int*      startA = (int*)     alloc((size_t)G * Nn * 4);
    int*      cntA   = (int*)     alloc((size_t)G * Nn * 4);
    int*      cntS   = (int*)     alloc((size_t)G * Nn * 4);
    int*      ordS   = (int*)     alloc((size_t)G * Nn * 4);
    int*      csr    = (int*)     alloc((size_t)G * 4 * QCAP * 4);
    unsigned* ellT   = (unsigned*)alloc((size_t)G * TSLOT * Nn * 4);
    unsigned char* t2f = (unsigned char*)alloc((size_t)G * Nn * 64);
    float*    emb    = (float*)   alloc((size_t)G * 64 * 4);
    float*    gi     = (float*)   alloc((size_t)G * 384 * 4);
    (void)ws_size; (void)in_sizes; (void)n_in; (void)out_size;

    hipLaunchKernelGGL(k_build,   dim3(480), dim3(1024), 0, stream, ei, dis, startA, cntA, csr, ellT, cntS, ordS, emb);
    hipLaunchKernelGGL(k_fused,   dim3(960), dim3(256), 0, stream, x, ellT, cntS, ordS, startA, csr, dis, W1, b1, W2, t2f);
    hipLaunchKernelGGL(k_agg64R3, dim3(960), dim3(512), 0, stream, t2f, ellT, cntS, ordS, startA, csr, dis, b2, emb);
    hipLaunchKernelGGL(k_gi,      dim3(G), dim3(384), 0, stream, emb, W_ih, b_ih, gi);
    hipLaunchKernelGGL(k_gru_seq, dim3(Bb), dim3(768), 0, stream, gi, W_hh, b_hh, fc_w, fc_b, out);
}

// Round 15
// 289.969 us; speedup vs baseline: 1.0885x; 1.0885x over previous
//
#include <hip/hip_runtime.h>
#include <math.h>

// Problem constants (fixed by the reference)
#define G    120     // B*T frames
#define Nn   2000    // nodes per frame
#define Ee   32000   // edges per frame
#define Tt   30
#define Bb   4
#define Fg   128     // GRU hidden
#define QCAP 9216    // CSR capacity per (frame,quadrant); expected 8000, sigma 78
#define TSLOT 48     // transposed-ELL slots/node: slot0=self + up to 47 edges

static __device__ __forceinline__ unsigned short f2bf(float f) {
    unsigned u = __float_as_uint(f);
    u += 0x7fffu + ((u >> 16) & 1u);          // round-to-nearest-even
    return (unsigned short)(u >> 16);
}

// ---------------- fp8 e4m3 encode/decode: HW builtins if available, SW fallback.
#if defined(__has_builtin)
#if __has_builtin(__builtin_amdgcn_cvt_f32_fp8) && __has_builtin(__builtin_amdgcn_cvt_pk_fp8_f32)
#define HW_FP8 1
#endif
#if __has_builtin(__builtin_amdgcn_cvt_pk_f32_fp8)
#define HW_FP8_PK 1
typedef float floatx2 __attribute__((ext_vector_type(2)));
#endif
#endif

static __device__ __forceinline__ unsigned fp8_enc_sw(float x) {
    unsigned s = (__float_as_uint(x) >> 24) & 0x80u;
    float ax = fminf(fabsf(x), 448.f);
    unsigned em;
    if (ax < 0.015625f) {
        em = (unsigned)__float2int_rn(ax * 512.f);
    } else {
        int e = (int)(__float_as_uint(ax) >> 23) - 127;
        float r = ax * __uint_as_float((unsigned)((130 - e) << 23));
        int q = __float2int_rn(r);
        em = (unsigned)(((e + 7) << 3) + (q - 8));
        em = min(em, 126u);
    }
    return s | em;
}
static __device__ __forceinline__ float fp8_dec_sw(unsigned b) {
    unsigned em = b & 0x7fu;
    float mag;
    if (em < 8u) mag = (float)em * 0.001953125f;
    else mag = __uint_as_float((((em >> 3) + 120u) << 23) | ((em & 7u) << 20));
    return (b & 0x80u) ? -mag : mag;
}
static __device__ __forceinline__ unsigned fp8_pack4(float a, float b, float c, float d) {
#ifdef HW_FP8
    int w = __builtin_amdgcn_cvt_pk_fp8_f32(a, b, 0, false);
    w = __builtin_amdgcn_cvt_pk_fp8_f32(c, d, w, true);
    return (unsigned)w;
#else
    return fp8_enc_sw(a) | (fp8_enc_sw(b) << 8) | (fp8_enc_sw(c) << 16) | (fp8_enc_sw(d) << 24);
#endif
}
static __device__ __forceinline__ void fp8x4_dec(unsigned dw, float* o) {
#ifdef HW_FP8_PK
    floatx2 lo = __builtin_amdgcn_cvt_pk_f32_fp8((int)dw, false);
    floatx2 hi = __builtin_amdgcn_cvt_pk_f32_fp8((int)dw, true);
    o[0] = lo[0]; o[1] = lo[1]; o[2] = hi[0]; o[3] = hi[1];
#else
    o[0] = fp8_dec_sw(dw & 0xffu);
    o[1] = fp8_dec_sw((dw >> 8) & 0xffu);
    o[2] = fp8_dec_sw((dw >> 16) & 0xffu);
    o[3] = fp8_dec_sw((dw >> 24) & 0xffu);
#endif
}

// ---- K1: fused build + per-quadrant degree counting-sort.
// Emits: dis/startA/cntA (by node, for overflow), sorted-column ellT, cntS/ordS
// (by sorted position), csr (global, only if overflow), emb zeroed.
__global__ void __launch_bounds__(1024, 1)
k_build(const int* __restrict__ ei, float* __restrict__ dis,
        int* __restrict__ startA, int* __restrict__ cntA,
        int* __restrict__ csr, unsigned* __restrict__ ellT,
        int* __restrict__ cntS, int* __restrict__ ordS,
        float* __restrict__ emb) {
    __shared__ int   hist[Nn];        // counts, then own-quadrant cursor
    __shared__ float disl[Nn];
    __shared__ int   ws[512];
    __shared__ int   csr_l[QCAP];
    __shared__ int   cntQ[500];
    __shared__ int   exQ[500];
    __shared__ int   nodeAt[500];     // sorted position -> local node idx
    __shared__ int   dh[64];          // degree histogram, then cursor
    __shared__ int   db[64];          // degree-bin exclusive base
    __shared__ int   ovfS;
    int i = blockIdx.x;               // 0..479
    int xcd = i & 7;
    int j = i >> 3;                   // 0..59
    int f15 = j >> 2;                 // 0..14
    int q = j & 3;
    int g = xcd * 15 + f15;
    int gq = g * 4 + q;
    int lo = q * 500;
    int tid = threadIdx.x;
    // P1: init
    for (int idx = tid; idx < Nn; idx += 1024) hist[idx] = 0;
    if (tid < 64) dh[tid] = 0;
    if (tid == 0) ovfS = 0;
    if (q == 0 && tid < 64) emb[g * 64 + tid] = 0.f;
    __syncthreads();
    // P2: full-frame histogram of destinations
    const int* srcp = ei + (size_t)g * 2 * Ee;
    const int* dstp = srcp + Ee;
    for (int it = tid; it < Ee / 4; it += 1024) {
        int4 d = reinterpret_cast<const int4*>(dstp)[it];
        atomicAdd(&hist[d.x], 1);
        atomicAdd(&hist[d.y], 1);
        atomicAdd(&hist[d.z], 1);
        atomicAdd(&hist[d.w], 1);
    }
    __syncthreads();
    // P3a: dis for all nodes; own-quadrant counts for scan
    for (int idx = tid; idx < Nn; idx += 1024) disl[idx] = rsqrtf((float)hist[idx] + 1.0f);
    int cnt = 0;
    if (tid < 512) ws[tid] = (tid < 500) ? hist[lo + tid] : 0;
    if (tid < 500) cnt = hist[lo + tid];
    __syncthreads();
    // P3b: inclusive scan over 512
    for (int off = 1; off < 512; off <<= 1) {
        int v = 0;
        if (tid < 512 && tid >= off) v = ws[tid - off];
        __syncthreads();
        if (tid < 512) ws[tid] += v;
        __syncthreads();
    }
    int ex = 0;
    if (tid < 500) ex = ws[tid] - cnt;
    // P3c: cursor + per-node arrays + degree histogram
    if (tid < 500) {
        hist[lo + tid] = ex;                       // cursor for P4
        cntQ[tid] = cnt;
        exQ[tid] = ex;
        if (cnt > TSLOT - 1) atomicMax(&ovfS, 1);
        atomicAdd(&dh[min(cnt, 63)], 1);
    }
    __syncthreads();
    // P3d: exclusive scan of degree bins (serial, 64 elems), then cursor=base
    if (tid == 0) {
        int s = 0;
        for (int b = 0; b < 64; ++b) { db[b] = s; s += dh[b]; }
    }
    __syncthreads();
    if (tid < 64) dh[tid] = db[tid];               // cursor per bin
    __syncthreads();
    // P3e: assign sorted positions
    if (tid < 500) {
        int p = atomicAdd(&dh[min(cnt, 63)], 1);
        nodeAt[p] = tid;
    }
    // P4: fill own-quadrant CSR in LDS
    for (int it = tid; it < Ee / 4; it += 1024) {
        int4 d = reinterpret_cast<const int4*>(dstp)[it];
        int4 s = reinterpret_cast<const int4*>(srcp)[it];
        if (d.x >= lo && d.x < lo + 500) { int p = atomicAdd(&hist[d.x], 1); if (p < QCAP) csr_l[p] = s.x; }
        if (d.y >= lo && d.y < lo + 500) { int p = atomicAdd(&hist[d.y], 1); if (p < QCAP) csr_l[p] = s.y; }
        if (d.z >= lo && d.z < lo + 500) { int p = atomicAdd(&hist[d.z], 1); if (p < QCAP) csr_l[p] = s.z; }
        if (d.w >= lo && d.w < lo + 500) { int p = atomicAdd(&hist[d.w], 1); if (p < QCAP) csr_l[p] = s.w; }
    }
    __syncthreads();
    // P5: per-node outputs. Thread t emits SORTED position t (node nodeAt[t]):
    // ELL stores coalesced across t; loop trip wave-uniform (sorted degrees).
    if (tid < 500) {
        // by-node arrays (overflow fallback + dis)
        int n_own = lo + tid;
        size_t gn_own = (size_t)g * Nn + n_own;
        cntA[gn_own] = cnt;
        startA[gn_own] = gq * QCAP + ex;
        dis[gn_own] = disl[n_own];
        // sorted emit
        int sl = nodeAt[tid];                      // local node idx at position tid
        int n2 = lo + sl;
        int cnt2 = cntQ[sl];
        int ex2 = exQ[sl];
        int c = q * 500 + tid;                     // frame-global sorted column
        size_t gc = (size_t)g * Nn + c;
        cntS[gc] = cnt2;
        ordS[gc] = n2;
        float dn2 = disl[n2];
        unsigned* et = ellT + (size_t)g * TSLOT * Nn + c;
        et[0] = (unsigned)n2 | ((unsigned)f2bf(dn2 * dn2) << 16);
        int m2 = min(cnt2, TSLOT - 1);
        for (int e = 0; e < m2; ++e) {
            int s = csr_l[ex2 + e];
            et[(size_t)(e + 1) * Nn] = (unsigned)s | ((unsigned)f2bf(disl[s] * dn2) << 16);
        }
    }
    __syncthreads();
    // P6: global CSR write only if some node overflowed (exact fallback path)
    if (ovfS) {
        int total = ws[511];
        int* cg = csr + (size_t)gq * QCAP;
        for (int it = tid; it < total; it += 1024) cg[it] = csr_l[it];
    }
}

// ---- K2: fully-fused per-lane pipeline: aggX (sorted-ELL gather of x, regs)
// -> h1 = relu(aggX@W1+b1) in regs -> t2 = h1@W2 in regs -> fp8 store by node.
// ALL array indices constant after unroll (no scratch demotion — R14's 76 MB
// WRITE_SIZE was h1r spilled to scratch via the partially-unrolled k-loop).
__global__ void __launch_bounds__(256)
k_fused(const float* __restrict__ x, const unsigned* __restrict__ ellT,
        const int* __restrict__ cntS, const int* __restrict__ ordS,
        const int* __restrict__ startA, const int* __restrict__ csr,
        const float* __restrict__ dis,
        const float* __restrict__ W1, const float* __restrict__ b1,
        const float* __restrict__ W2, unsigned char* __restrict__ t2f) {
    int i = blockIdx.x;                 // 960 = 8 xcd * 15 frames * 8 pos-blocks
    int xcd = i & 7;
    int j = i >> 3;                     // 0..119
    int g = xcd * 15 + (j >> 3);
    int blk = j & 7;
    int p = blk * 256 + threadIdx.x;    // sorted position
    bool valid = (p < Nn);
    size_t gp = (size_t)g * Nn + (valid ? p : 0);
    int n = valid ? ordS[gp] : 0;
    int cnt = valid ? cntS[gp] : 0;
    int myc = valid ? (min(cnt, TSLOT - 1) + 1) : 0;
    // phase 0: aggregate raw x (8-dim) into registers via sorted ELL
    float aX[8];
#pragma unroll
    for (int k = 0; k < 8; ++k) aX[k] = 0.f;
    {
        const unsigned* et = ellT + (size_t)g * TSLOT * Nn + (valid ? p : 0);
        const float4* x4 = reinterpret_cast<const float4*>(x + (size_t)g * Nn * 8);
        for (int e = 0; e < TSLOT; ++e) {
            if (!__any(e < myc)) break;
            if (e < myc) {
                unsigned u = et[(size_t)e * Nn];
                float w = __uint_as_float(u & 0xffff0000u);
                int s = u & 0xffffu;
                float4 r0 = x4[s * 2], r1 = x4[s * 2 + 1];
                aX[0] += r0.x * w; aX[1] += r0.y * w; aX[2] += r0.z * w; aX[3] += r0.w * w;
                aX[4] += r1.x * w; aX[5] += r1.y * w; aX[6] += r1.z * w; aX[7] += r1.w * w;
            }
        }
        if (cnt > TSLOT - 1) {          // rare overflow (deg > 47)
            size_t gn = (size_t)g * Nn + n;
            float dn = dis[gn];
            int start = startA[gn];
            const float* dsg = dis + (size_t)g * Nn;
            for (int e = TSLOT - 1; e < cnt; ++e) {
                int s = csr[start + e];
                float w = dsg[s] * dn;
                float4 r0 = x4[s * 2], r1 = x4[s * 2 + 1];
                aX[0] += r0.x * w; aX[1] += r0.y * w; aX[2] += r0.z * w; aX[3] += r0.w * w;
                aX[4] += r1.x * w; aX[5] += r1.y * w; aX[6] += r1.z * w; aX[7] += r1.w * w;
            }
        }
    }
    // phase 1: h1 = relu(aX @ W1 + b1), W1/b1 uniform scalar loads, full unroll
    float h1r[64];
    {
        const float4* b14 = reinterpret_cast<const float4*>(b1);
#pragma unroll
        for (int f4 = 0; f4 < 16; ++f4) {
            float4 b = b14[f4];
            h1r[4 * f4 + 0] = b.x; h1r[4 * f4 + 1] = b.y;
            h1r[4 * f4 + 2] = b.z; h1r[4 * f4 + 3] = b.w;
        }
        const float4* W14 = reinterpret_cast<const float4*>(W1);
#pragma unroll
        for (int k = 0; k < 8; ++k) {
            float hk = aX[k];
#pragma unroll
            for (int f4 = 0; f4 < 16; ++f4) {
                float4 w = W14[k * 16 + f4];
                h1r[4 * f4 + 0] += hk * w.x; h1r[4 * f4 + 1] += hk * w.y;
                h1r[4 * f4 + 2] += hk * w.z; h1r[4 * f4 + 3] += hk * w.w;
            }
        }
#pragma unroll
        for (int f = 0; f < 64; ++f) h1r[f] = fmaxf(h1r[f], 0.f);
    }
    // phase 2: t2 = h1 @ W2 (fp8 out), two 32-feature halves (caps live VGPRs),
    // FULL unroll everywhere -> constant indices -> no scratch.
    uint4 oh[2][2];
    {
        const float4* W24 = reinterpret_cast<const float4*>(W2);
#pragma unroll
        for (int hf = 0; hf < 2; ++hf) {
            float acch[32];
#pragma unroll
            for (int f = 0; f < 32; ++f) acch[f] = 0.f;
#pragma unroll
            for (int k = 0; k < 64; ++k) {
                float hk = h1r[k];
#pragma unroll
                for (int f4 = 0; f4 < 8; ++f4) {
                    float4 w = W24[k * 16 + hf * 8 + f4];
                    acch[4 * f4 + 0] += hk * w.x; acch[4 * f4 + 1] += hk * w.y;
                    acch[4 * f4 + 2] += hk * w.z; acch[4 * f4 + 3] += hk * w.w;
                }
            }
            oh[hf][0].x = fp8_pack4(acch[0],  acch[1],  acch[2],  acch[3]);
            oh[hf][0].y = fp8_pack4(acch[4],  acch[5],  acch[6],  acch[7]);
            oh[hf][0].z = fp8_pack4(acch[8],  acch[9],  acch[10], acch[11]);
            oh[hf][0].w = fp8_pack4(acch[12], acch[13], acch[14], acch[15]);
            oh[hf][1].x = fp8_pack4(acch[16], acch[17], acch[18], acch[19]);
            oh[hf][1].y = fp8_pack4(acch[20], acch[21], acch[22], acch[23]);
            oh[hf][1].z = fp8_pack4(acch[24], acch[25], acch[26], acch[27]);
            oh[hf][1].w = fp8_pack4(acch[28], acch[29], acch[30], acch[31]);
        }
    }
    if (valid) {
        uint4* op = reinterpret_cast<uint4*>(t2f + ((size_t)g * Nn + n) * 64);
        op[0] = oh[0][0]; op[1] = oh[0][1]; op[2] = oh[1][0]; op[3] = oh[1][1];
    }
}

// ---- K3: sorted node-per-lane aggregation of t2 (fp8) + relu + mean-pool,
// feature-split: 512 thr = 8 waves; wave = 64 sorted positions x 32 features.
__global__ void __launch_bounds__(512)
k_agg64R3(const unsigned char* __restrict__ t2f, const unsigned* __restrict__ ellT,
          const int* __restrict__ cntS, const int* __restrict__ ordS,
          const int* __restrict__ startA, const int* __restrict__ csr,
          const float* __restrict__ dis, const float* __restrict__ bias,
          float* __restrict__ emb) {
    int i = blockIdx.x;                 // 960 = 8 xcd * 15 frames * 8 pos-blocks
    int xcd = i & 7;
    int j = i >> 3;                     // 0..119
    int g = xcd * 15 + (j >> 3);
    int blk = j & 7;
    int tid = threadIdx.x;              // 0..511
    int w = tid >> 6;                   // wave 0..7
    int lane = tid & 63;
    int ng = w >> 1;                    // position group 0..3
    int half = w & 1;                   // feature half
    int p = blk * 256 + ng * 64 + lane; // sorted position
    bool valid = (p < Nn);
    size_t gp = (size_t)g * Nn + (valid ? p : 0);
    int cnt = valid ? cntS[gp] : 0;
    int myc = valid ? (min(cnt, TSLOT - 1) + 1) : 0;
    float acc[32];
#pragma unroll
    for (int k = 0; k < 32; ++k) acc[k] = 0.f;
    const unsigned* et = ellT + (size_t)g * TSLOT * Nn + (valid ? p : 0);
    const uint4* t2g = reinterpret_cast<const uint4*>(t2f + (size_t)g * Nn * 64);
#define ROWFMA(dw, base) { float o_[4]; fp8x4_dec(dw, o_); \
    acc[base + 0] += o_[0] * wt; acc[base + 1] += o_[1] * wt; \
    acc[base + 2] += o_[2] * wt; acc[base + 3] += o_[3] * wt; }
    for (int e = 0; e < TSLOT; ++e) {
        if (!__any(e < myc)) break;
        if (e < myc) {
            unsigned u = et[(size_t)e * Nn];
            float wt = __uint_as_float(u & 0xffff0000u);
            int s = u & 0xffffu;
            const uint4* row = t2g + s * 4 + half * 2;
            uint4 r0 = row[0], r1 = row[1];
            ROWFMA(r0.x, 0)  ROWFMA(r0.y, 4)  ROWFMA(r0.z, 8)  ROWFMA(r0.w, 12)
            ROWFMA(r1.x, 16) ROWFMA(r1.y, 20) ROWFMA(r1.z, 24) ROWFMA(r1.w, 28)
        }
    }
    if (cnt > TSLOT - 1) {              // rare overflow (deg > 47)
        int n = ordS[gp];
        size_t gn = (size_t)g * Nn + n;
        float dn = dis[gn];
        int start = startA[gn];
        const float* dsg = dis + (size_t)g * Nn;
        for (int e = TSLOT - 1; e < cnt; ++e) {
            int s = csr[start + e];
            float wt = dsg[s] * dn;
            const uint4* row = t2g + s * 4 + half * 2;
            uint4 r0 = row[0], r1 = row[1];
            ROWFMA(r0.x, 0)  ROWFMA(r0.y, 4)  ROWFMA(r0.z, 8)  ROWFMA(r0.w, 12)
            ROWFMA(r1.x, 16) ROWFMA(r1.y, 20) ROWFMA(r1.z, 24) ROWFMA(r1.w, 28)
        }
    }
#undef ROWFMA
    // bias + relu + wave-pool (butterfly per feature), then 1 atomic per lane
    float mypool = 0.f;
#pragma unroll
    for (int k = 0; k < 32; ++k) {
        float v = valid ? fmaxf(acc[k] + bias[half * 32 + k], 0.f) : 0.f;
        v += __shfl_xor(v, 1);  v += __shfl_xor(v, 2);  v += __shfl_xor(v, 4);
        v += __shfl_xor(v, 8);  v += __shfl_xor(v, 16); v += __shfl_xor(v, 32);
        if (lane == k) mypool = v;
    }
    if (lane < 32) atomicAdd(&emb[g * 64 + half * 32 + lane], mypool * (1.0f / Nn));
}

// ---- K4: gi[g][384] = emb[g] @ W_ih^T + b_ih (parallel over frames)
__global__ void k_gi(const float* __restrict__ emb, const float* __restrict__ W_ih,
                     const float* __restrict__ b_ih, float* __restrict__ gi) {
    __shared__ float xs[64];
    int g = blockIdx.x;          // g = b*Tt + t
    int j = threadIdx.x;         // 0..383
    if (j < 64) xs[j] = emb[g * 64 + j];
    __syncthreads();
    float a0 = 0.f, a1 = 0.f, a2 = 0.f, a3 = 0.f;
    const float* wr = W_ih + j * 64;
#pragma unroll
    for (int k = 0; k < 16; ++k) {
        a0 += wr[4 * k + 0] * xs[4 * k + 0];
        a1 += wr[4 * k + 1] * xs[4 * k + 1];
        a2 += wr[4 * k + 2] * xs[4 * k + 2];
        a3 += wr[4 * k + 3] * xs[4 * k + 3];
    }
    gi[(size_t)g * 384 + j] = b_ih[j] + ((a0 + a1) + (a2 + a3));
}

// ---- K5: sequential GRU over T, one block per batch, W_hh in regs + final FC
__global__ void __launch_bounds__(768, 1)
k_gru_seq(const float* __restrict__ gi, const float* __restrict__ W_hh,
          const float* __restrict__ b_hh, const float* __restrict__ fc_w,
          const float* __restrict__ fc_b, float* __restrict__ out) {
    __shared__ float h[Fg];
    __shared__ float part[768];
    int b = blockIdx.x;                  // batch
    int tid = threadIdx.x;               // 0..767
    int row = tid >> 1;                  // gate-row 0..383
    int half = tid & 1;                  // which 64-slice of k
    float w[64];
    const float* wr = W_hh + (size_t)row * Fg + half * 64;
#pragma unroll
    for (int i = 0; i < 64; ++i) w[i] = wr[i];
    if (tid < Fg) h[tid] = 0.f;
    __syncthreads();
    for (int t = 0; t < Tt; ++t) {
        const float* hh = &h[half * 64];
        float a0 = 0.f, a1 = 0.f, a2 = 0.f, a3 = 0.f;
#pragma unroll
        for (int i = 0; i < 16; ++i) {
            a0 += w[4 * i + 0] * hh[4 * i + 0];
            a1 += w[4 * i + 1] * hh[4 * i + 1];
            a2 += w[4 * i + 2] * hh[4 * i + 2];
            a3 += w[4 * i + 3] * hh[4 * i + 3];
        }
        part[tid] = (a0 + a1) + (a2 + a3);
        __syncthreads();
        if (tid < Fg) {
            int j = tid;
            const float* gib = gi + ((size_t)b * Tt + t) * 384;
            float hr = b_hh[j]       + part[2 * j]           + part[2 * j + 1];
            float hz = b_hh[128 + j] + part[2 * (128 + j)]   + part[2 * (128 + j) + 1];
            float hn = b_hh[256 + j] + part[2 * (256 + j)]   + part[2 * (256 + j) + 1];
            float r  = 1.f / (1.f + expf(-(gib[j] + hr)));
            float z  = 1.f / (1.f + expf(-(gib[128 + j] + hz)));
            float nn = tanhf(gib[256 + j] + r * hn);
            h[j] = (1.f - z) * nn + z * h[j];
        }
        __syncthreads();
    }
    if (tid < 2) {
        float acc = fc_b[tid];
        for (int k = 0; k < Fg; ++k) acc += fc_w[tid * Fg + k] * h[k];
        out[b * 2 + tid] = acc;
    }
}

// ----------------------------------------------------------------- launcher
extern "C" void kernel_launch(void* const* d_in, const int* in_sizes, int n_in,
                              void* d_out, int out_size, void* d_ws, size_t ws_size,
                              hipStream_t stream) {
    const float* x     = (const float*)d_in[0];
    const int*   ei    = (const int*)  d_in[1];
    const float* W1    = (const float*)d_in[2];
    const float* b1    = (const float*)d_in[3];
    const float* W2    = (const float*)d_in[4];
    const float* b2    = (const float*)d_in[5];
    const float* W_ih  = (const float*)d_in[6];
    const float* W_hh  = (const float*)d_in[7];
    const float* b_ih  = (const float*)d_in[8];
    const float* b_hh  = (const float*)d_in[9];
    const float* fc_w  = (const float*)d_in[10];
    const float* fc_b  = (const float*)d_in[11];
    float* out = (float*)d_out;

    char* ws = (char*)d_ws;
    size_t off = 0;
    auto alloc = [&](size_t bytes) -> void* {
        void* p = ws + off;
        off = (off + bytes + 255) & ~(size_t)255;
        return p;
    };
    float*    dis    = (float*)   alloc((size_t)G * Nn * 4);
    int*      startA = (int*)     alloc((size_t)G * Nn * 4);
    int*      cntA   = (int*)     alloc((size_t)G * Nn * 4);
    int*      cntS   = (int*)     alloc((size_t)G * Nn * 4);
    int*      ordS   = (int*)     alloc((size_t)G * Nn * 4);
    int*      csr    = (int*)     alloc((size_t)G * 4 * QCAP * 4);
    unsigned* ellT   = (unsigned*)alloc((size_t)G * TSLOT * Nn * 4);
    unsigned char* t2f = (unsigned char*)alloc((size_t)G * Nn * 64);
    float*    emb    = (float*)   alloc((size_t)G * 64 * 4);
    float*    gi     = (float*)   alloc((size_t)G * 384 * 4);
    (void)ws_size; (void)in_sizes; (void)n_in; (void)out_size;

    hipLaunchKernelGGL(k_build,   dim3(480), dim3(1024), 0, stream, ei, dis, startA, cntA, csr, ellT, cntS, ordS, emb);
    hipLaunchKernelGGL(k_fused,   dim3(960), dim3(256), 0, stream, x, ellT, cntS, ordS, startA, csr, dis, W1, b1, W2, t2f);
    hipLaunchKernelGGL(k_agg64R3, dim3(960), dim3(512), 0, stream, t2f, ellT, cntS, ordS, startA, csr, dis, b2, emb);
    hipLaunchKernelGGL(k_gi,      dim3(G), dim3(384), 0, stream, emb, W_ih, b_ih, gi);
    hipLaunchKernelGGL(k_gru_seq, dim3(Bb), dim3(768), 0, stream, gi, W_hh, b_hh, fc_w, fc_b, out);
}

// Round 16
// 280.212 us; speedup vs baseline: 1.1264x; 1.0348x over previous
//
#include <hip/hip_runtime.h>
#include <math.h>

// Problem constants (fixed by the reference)
#define G    120     // B*T frames
#define Nn   2000    // nodes per frame
#define Ee   32000   // edges per frame
#define Tt   30
#define Bb   4
#define Fg   128     // GRU hidden
#define QCAP 9216    // CSR capacity per (frame,quadrant); expected 8000, sigma 78
#define TSLOT 48     // transposed-ELL slots/node: slot0=self + up to 47 edges

static __device__ __forceinline__ unsigned short f2bf(float f) {
    unsigned u = __float_as_uint(f);
    u += 0x7fffu + ((u >> 16) & 1u);          // round-to-nearest-even
    return (unsigned short)(u >> 16);
}

// ---------------- fp8 e4m3 encode/decode: HW builtins if available, SW fallback.
#if defined(__has_builtin)
#if __has_builtin(__builtin_amdgcn_cvt_f32_fp8) && __has_builtin(__builtin_amdgcn_cvt_pk_fp8_f32)
#define HW_FP8 1
#endif
#if __has_builtin(__builtin_amdgcn_cvt_pk_f32_fp8)
#define HW_FP8_PK 1
typedef float floatx2 __attribute__((ext_vector_type(2)));
#endif
#endif

static __device__ __forceinline__ unsigned fp8_enc_sw(float x) {
    unsigned s = (__float_as_uint(x) >> 24) & 0x80u;
    float ax = fminf(fabsf(x), 448.f);
    unsigned em;
    if (ax < 0.015625f) {
        em = (unsigned)__float2int_rn(ax * 512.f);
    } else {
        int e = (int)(__float_as_uint(ax) >> 23) - 127;
        float r = ax * __uint_as_float((unsigned)((130 - e) << 23));
        int q = __float2int_rn(r);
        em = (unsigned)(((e + 7) << 3) + (q - 8));
        em = min(em, 126u);
    }
    return s | em;
}
static __device__ __forceinline__ float fp8_dec_sw(unsigned b) {
    unsigned em = b & 0x7fu;
    float mag;
    if (em < 8u) mag = (float)em * 0.001953125f;
    else mag = __uint_as_float((((em >> 3) + 120u) << 23) | ((em & 7u) << 20));
    return (b & 0x80u) ? -mag : mag;
}
static __device__ __forceinline__ unsigned fp8_pack4(float a, float b, float c, float d) {
#ifdef HW_FP8
    int w = __builtin_amdgcn_cvt_pk_fp8_f32(a, b, 0, false);
    w = __builtin_amdgcn_cvt_pk_fp8_f32(c, d, w, true);
    return (unsigned)w;
#else
    return fp8_enc_sw(a) | (fp8_enc_sw(b) << 8) | (fp8_enc_sw(c) << 16) | (fp8_enc_sw(d) << 24);
#endif
}
static __device__ __forceinline__ void fp8x4_dec(unsigned dw, float* o) {
#ifdef HW_FP8_PK
    floatx2 lo = __builtin_amdgcn_cvt_pk_f32_fp8((int)dw, false);
    floatx2 hi = __builtin_amdgcn_cvt_pk_f32_fp8((int)dw, true);
    o[0] = lo[0]; o[1] = lo[1]; o[2] = hi[0]; o[3] = hi[1];
#else
    o[0] = fp8_dec_sw(dw & 0xffu);
    o[1] = fp8_dec_sw((dw >> 8) & 0xffu);
    o[2] = fp8_dec_sw((dw >> 16) & 0xffu);
    o[3] = fp8_dec_sw((dw >> 24) & 0xffu);
#endif
}

// ---- K1: fused build + per-quadrant degree counting-sort.
// Emits: dis/startA/cntA (by node, for overflow), sorted-column ellT, cntS/ordS
// (by sorted position), csr (global, only if overflow), emb zeroed.
__global__ void __launch_bounds__(1024, 1)
k_build(const int* __restrict__ ei, float* __restrict__ dis,
        int* __restrict__ startA, int* __restrict__ cntA,
        int* __restrict__ csr, unsigned* __restrict__ ellT,
        int* __restrict__ cntS, int* __restrict__ ordS,
        float* __restrict__ emb) {
    __shared__ int   hist[Nn];        // counts, then own-quadrant cursor
    __shared__ float disl[Nn];
    __shared__ int   ws[512];
    __shared__ int   csr_l[QCAP];
    __shared__ int   cntQ[500];
    __shared__ int   exQ[500];
    __shared__ int   nodeAt[500];     // sorted position -> local node idx
    __shared__ int   dh[64];          // degree histogram, then cursor
    __shared__ int   db[64];          // degree-bin exclusive base
    __shared__ int   ovfS;
    int i = blockIdx.x;               // 0..479
    int xcd = i & 7;
    int j = i >> 3;                   // 0..59
    int f15 = j >> 2;                 // 0..14
    int q = j & 3;
    int g = xcd * 15 + f15;
    int gq = g * 4 + q;
    int lo = q * 500;
    int tid = threadIdx.x;
    // P1: init
    for (int idx = tid; idx < Nn; idx += 1024) hist[idx] = 0;
    if (tid < 64) dh[tid] = 0;
    if (tid == 0) ovfS = 0;
    if (q == 0 && tid < 64) emb[g * 64 + tid] = 0.f;
    __syncthreads();
    // P2: full-frame histogram of destinations
    const int* srcp = ei + (size_t)g * 2 * Ee;
    const int* dstp = srcp + Ee;
    for (int it = tid; it < Ee / 4; it += 1024) {
        int4 d = reinterpret_cast<const int4*>(dstp)[it];
        atomicAdd(&hist[d.x], 1);
        atomicAdd(&hist[d.y], 1);
        atomicAdd(&hist[d.z], 1);
        atomicAdd(&hist[d.w], 1);
    }
    __syncthreads();
    // P3a: dis for all nodes; own-quadrant counts for scan
    for (int idx = tid; idx < Nn; idx += 1024) disl[idx] = rsqrtf((float)hist[idx] + 1.0f);
    int cnt = 0;
    if (tid < 512) ws[tid] = (tid < 500) ? hist[lo + tid] : 0;
    if (tid < 500) cnt = hist[lo + tid];
    __syncthreads();
    // P3b: inclusive scan over 512
    for (int off = 1; off < 512; off <<= 1) {
        int v = 0;
        if (tid < 512 && tid >= off) v = ws[tid - off];
        __syncthreads();
        if (tid < 512) ws[tid] += v;
        __syncthreads();
    }
    int ex = 0;
    if (tid < 500) ex = ws[tid] - cnt;
    // P3c: cursor + per-node arrays + degree histogram
    if (tid < 500) {
        hist[lo + tid] = ex;                       // cursor for P4
        cntQ[tid] = cnt;
        exQ[tid] = ex;
        if (cnt > TSLOT - 1) atomicMax(&ovfS, 1);
        atomicAdd(&dh[min(cnt, 63)], 1);
    }
    __syncthreads();
    // P3d: exclusive scan of degree bins (serial, 64 elems), then cursor=base
    if (tid == 0) {
        int s = 0;
        for (int b = 0; b < 64; ++b) { db[b] = s; s += dh[b]; }
    }
    __syncthreads();
    if (tid < 64) dh[tid] = db[tid];               // cursor per bin
    __syncthreads();
    // P3e: assign sorted positions
    if (tid < 500) {
        int p = atomicAdd(&dh[min(cnt, 63)], 1);
        nodeAt[p] = tid;
    }
    // P4: fill own-quadrant CSR in LDS
    for (int it = tid; it < Ee / 4; it += 1024) {
        int4 d = reinterpret_cast<const int4*>(dstp)[it];
        int4 s = reinterpret_cast<const int4*>(srcp)[it];
        if (d.x >= lo && d.x < lo + 500) { int p = atomicAdd(&hist[d.x], 1); if (p < QCAP) csr_l[p] = s.x; }
        if (d.y >= lo && d.y < lo + 500) { int p = atomicAdd(&hist[d.y], 1); if (p < QCAP) csr_l[p] = s.y; }
        if (d.z >= lo && d.z < lo + 500) { int p = atomicAdd(&hist[d.z], 1); if (p < QCAP) csr_l[p] = s.z; }
        if (d.w >= lo && d.w < lo + 500) { int p = atomicAdd(&hist[d.w], 1); if (p < QCAP) csr_l[p] = s.w; }
    }
    __syncthreads();
    // P5: per-node outputs. Thread t emits SORTED position t (node nodeAt[t]):
    // ELL stores coalesced across t; loop trip wave-uniform (sorted degrees).
    if (tid < 500) {
        // by-node arrays (overflow fallback + dis)
        int n_own = lo + tid;
        size_t gn_own = (size_t)g * Nn + n_own;
        cntA[gn_own] = cnt;
        startA[gn_own] = gq * QCAP + ex;
        dis[gn_own] = disl[n_own];
        // sorted emit
        int sl = nodeAt[tid];                      // local node idx at position tid
        int n2 = lo + sl;
        int cnt2 = cntQ[sl];
        int ex2 = exQ[sl];
        int c = q * 500 + tid;                     // frame-global sorted column
        size_t gc = (size_t)g * Nn + c;
        cntS[gc] = cnt2;
        ordS[gc] = n2;
        float dn2 = disl[n2];
        unsigned* et = ellT + (size_t)g * TSLOT * Nn + c;
        et[0] = (unsigned)n2 | ((unsigned)f2bf(dn2 * dn2) << 16);
        int m2 = min(cnt2, TSLOT - 1);
        for (int e = 0; e < m2; ++e) {
            int s = csr_l[ex2 + e];
            et[(size_t)(e + 1) * Nn] = (unsigned)s | ((unsigned)f2bf(disl[s] * dn2) << 16);
        }
    }
    __syncthreads();
    // P6: global CSR write only if some node overflowed (exact fallback path)
    if (ovfS) {
        int total = ws[511];
        int* cg = csr + (size_t)gq * QCAP;
        for (int it = tid; it < total; it += 1024) cg[it] = csr_l[it];
    }
}

// ---- K2: fully-fused per-lane pipeline: aggX (sorted-ELL gather of x, regs)
// -> h1 = relu(aggX@W1+b1) in regs -> t2 = h1@W2 in regs -> fp8 store by node.
// ALL array indices constant after unroll (no scratch demotion).
__global__ void __launch_bounds__(256)
k_fused(const float* __restrict__ x, const unsigned* __restrict__ ellT,
        const int* __restrict__ cntS, const int* __restrict__ ordS,
        const int* __restrict__ startA, const int* __restrict__ csr,
        const float* __restrict__ dis,
        const float* __restrict__ W1, const float* __restrict__ b1,
        const float* __restrict__ W2, unsigned char* __restrict__ t2f) {
    int i = blockIdx.x;                 // 960 = 8 xcd * 15 frames * 8 pos-blocks
    int xcd = i & 7;
    int j = i >> 3;                     // 0..119
    int g = xcd * 15 + (j >> 3);
    int blk = j & 7;
    int p = blk * 256 + threadIdx.x;    // sorted position
    bool valid = (p < Nn);
    size_t gp = (size_t)g * Nn + (valid ? p : 0);
    int n = valid ? ordS[gp] : 0;
    int cnt = valid ? cntS[gp] : 0;
    int myc = valid ? (min(cnt, TSLOT - 1) + 1) : 0;
    // phase 0: aggregate raw x (8-dim) into registers via sorted ELL
    float aX[8];
#pragma unroll
    for (int k = 0; k < 8; ++k) aX[k] = 0.f;
    {
        const unsigned* et = ellT + (size_t)g * TSLOT * Nn + (valid ? p : 0);
        const float4* x4 = reinterpret_cast<const float4*>(x + (size_t)g * Nn * 8);
        for (int e = 0; e < TSLOT; ++e) {
            if (!__any(e < myc)) break;
            if (e < myc) {
                unsigned u = et[(size_t)e * Nn];
                float w = __uint_as_float(u & 0xffff0000u);
                int s = u & 0xffffu;
                float4 r0 = x4[s * 2], r1 = x4[s * 2 + 1];
                aX[0] += r0.x * w; aX[1] += r0.y * w; aX[2] += r0.z * w; aX[3] += r0.w * w;
                aX[4] += r1.x * w; aX[5] += r1.y * w; aX[6] += r1.z * w; aX[7] += r1.w * w;
            }
        }
        if (cnt > TSLOT - 1) {          // rare overflow (deg > 47)
            size_t gn = (size_t)g * Nn + n;
            float dn = dis[gn];
            int start = startA[gn];
            const float* dsg = dis + (size_t)g * Nn;
            for (int e = TSLOT - 1; e < cnt; ++e) {
                int s = csr[start + e];
                float w = dsg[s] * dn;
                float4 r0 = x4[s * 2], r1 = x4[s * 2 + 1];
                aX[0] += r0.x * w; aX[1] += r0.y * w; aX[2] += r0.z * w; aX[3] += r0.w * w;
                aX[4] += r1.x * w; aX[5] += r1.y * w; aX[6] += r1.z * w; aX[7] += r1.w * w;
            }
        }
    }
    // phase 1: h1 = relu(aX @ W1 + b1), W1/b1 uniform scalar loads, full unroll
    float h1r[64];
    {
        const float4* b14 = reinterpret_cast<const float4*>(b1);
#pragma unroll
        for (int f4 = 0; f4 < 16; ++f4) {
            float4 b = b14[f4];
            h1r[4 * f4 + 0] = b.x; h1r[4 * f4 + 1] = b.y;
            h1r[4 * f4 + 2] = b.z; h1r[4 * f4 + 3] = b.w;
        }
        const float4* W14 = reinterpret_cast<const float4*>(W1);
#pragma unroll
        for (int k = 0; k < 8; ++k) {
            float hk = aX[k];
#pragma unroll
            for (int f4 = 0; f4 < 16; ++f4) {
                float4 w = W14[k * 16 + f4];
                h1r[4 * f4 + 0] += hk * w.x; h1r[4 * f4 + 1] += hk * w.y;
                h1r[4 * f4 + 2] += hk * w.z; h1r[4 * f4 + 3] += hk * w.w;
            }
        }
#pragma unroll
        for (int f = 0; f < 64; ++f) h1r[f] = fmaxf(h1r[f], 0.f);
    }
    // phase 2: t2 = h1 @ W2 (fp8 out), two 32-feature halves (caps live VGPRs),
    // FULL unroll everywhere -> constant indices -> no scratch.
    uint4 oh[2][2];
    {
        const float4* W24 = reinterpret_cast<const float4*>(W2);
#pragma unroll
        for (int hf = 0; hf < 2; ++hf) {
            float acch[32];
#pragma unroll
            for (int f = 0; f < 32; ++f) acch[f] = 0.f;
#pragma unroll
            for (int k = 0; k < 64; ++k) {
                float hk = h1r[k];
#pragma unroll
                for (int f4 = 0; f4 < 8; ++f4) {
                    float4 w = W24[k * 16 + hf * 8 + f4];
                    acch[4 * f4 + 0] += hk * w.x; acch[4 * f4 + 1] += hk * w.y;
                    acch[4 * f4 + 2] += hk * w.z; acch[4 * f4 + 3] += hk * w.w;
                }
            }
            oh[hf][0].x = fp8_pack4(acch[0],  acch[1],  acch[2],  acch[3]);
            oh[hf][0].y = fp8_pack4(acch[4],  acch[5],  acch[6],  acch[7]);
            oh[hf][0].z = fp8_pack4(acch[8],  acch[9],  acch[10], acch[11]);
            oh[hf][0].w = fp8_pack4(acch[12], acch[13], acch[14], acch[15]);
            oh[hf][1].x = fp8_pack4(acch[16], acch[17], acch[18], acch[19]);
            oh[hf][1].y = fp8_pack4(acch[20], acch[21], acch[22], acch[23]);
            oh[hf][1].z = fp8_pack4(acch[24], acch[25], acch[26], acch[27]);
            oh[hf][1].w = fp8_pack4(acch[28], acch[29], acch[30], acch[31]);
        }
    }
    if (valid) {
        uint4* op = reinterpret_cast<uint4*>(t2f + ((size_t)g * Nn + n) * 64);
        op[0] = oh[0][0]; op[1] = oh[0][1]; op[2] = oh[1][0]; op[3] = oh[1][1];
    }
}

// ---- K3: LDS-staged aggregation of t2 (fp8) + relu + mean-pool.
// Whole frame t2 = 2000 x 64 B = 128 KB fits LDS; staged ONCE; gathers become
// ds_read_b128 (64 lanes served per instr — removes the L1 line-throughput
// ceiling that capped R15's k_agg64R3 at 78 us). 2 blocks/frame, XCD-pinned;
// wave = 64 sorted positions (node-per-lane, full row).
__global__ void __launch_bounds__(512, 1)
k_aggF(const unsigned char* __restrict__ t2f, const unsigned* __restrict__ ellT,
       const int* __restrict__ cntS, const int* __restrict__ ordS,
       const int* __restrict__ startA, const int* __restrict__ csr,
       const float* __restrict__ dis, const float* __restrict__ bias,
       float* __restrict__ emb) {
    __shared__ uint4 stage[Nn * 4];     // 128000 B
    int i = blockIdx.x;                 // 240 = 8 xcd * 15 frames * 2 halves
    int xcd = i & 7;
    int j = i >> 3;                     // 0..29
    int g = xcd * 15 + (j >> 1);
    int half = j & 1;
    int tid = threadIdx.x;
    int w = tid >> 6, lane = tid & 63;
    // stage entire frame t2 (fp8) into LDS, coalesced
    {
        const uint4* src = reinterpret_cast<const uint4*>(t2f + (size_t)g * Nn * 64);
        for (int it = tid; it < Nn * 4; it += 512) stage[it] = src[it];
    }
    __syncthreads();
    float pool = 0.f;                   // lane k accumulates pooled feature k
#define ROWFMA(dw, base) { float o_[4]; fp8x4_dec(dw, o_); \
    acc[base + 0] += o_[0] * wt; acc[base + 1] += o_[1] * wt; \
    acc[base + 2] += o_[2] * wt; acc[base + 3] += o_[3] * wt; }
    for (int itg = 0; itg < 2; ++itg) {
        int grp = w + 8 * itg;          // 0..15
        int po = grp * 64 + lane;       // 0..1023
        int p = half * 1000 + po;       // sorted position
        bool valid = (po < 1000);
        size_t gp = (size_t)g * Nn + (valid ? p : 0);
        int cnt = valid ? cntS[gp] : 0;
        int myc = valid ? (min(cnt, TSLOT - 1) + 1) : 0;
        float acc[64];
#pragma unroll
        for (int k = 0; k < 64; ++k) acc[k] = 0.f;
        const unsigned* et = ellT + (size_t)g * TSLOT * Nn + (valid ? p : 0);
        for (int e = 0; e < TSLOT; ++e) {
            if (!__any(e < myc)) break;
            if (e < myc) {
                unsigned u = et[(size_t)e * Nn];
                float wt = __uint_as_float(u & 0xffff0000u);
                int s = u & 0xffffu;
                uint4 r0 = stage[s * 4], r1 = stage[s * 4 + 1];
                uint4 r2 = stage[s * 4 + 2], r3 = stage[s * 4 + 3];
                ROWFMA(r0.x, 0)  ROWFMA(r0.y, 4)  ROWFMA(r0.z, 8)  ROWFMA(r0.w, 12)
                ROWFMA(r1.x, 16) ROWFMA(r1.y, 20) ROWFMA(r1.z, 24) ROWFMA(r1.w, 28)
                ROWFMA(r2.x, 32) ROWFMA(r2.y, 36) ROWFMA(r2.z, 40) ROWFMA(r2.w, 44)
                ROWFMA(r3.x, 48) ROWFMA(r3.y, 52) ROWFMA(r3.z, 56) ROWFMA(r3.w, 60)
            }
        }
        if (cnt > TSLOT - 1) {          // rare overflow (deg > 47)
            int n = ordS[gp];
            size_t gn = (size_t)g * Nn + n;
            float dn = dis[gn];
            int start = startA[gn];
            const float* dsg = dis + (size_t)g * Nn;
            for (int e = TSLOT - 1; e < cnt; ++e) {
                int s = csr[start + e];
                float wt = dsg[s] * dn;
                uint4 r0 = stage[s * 4], r1 = stage[s * 4 + 1];
                uint4 r2 = stage[s * 4 + 2], r3 = stage[s * 4 + 3];
                ROWFMA(r0.x, 0)  ROWFMA(r0.y, 4)  ROWFMA(r0.z, 8)  ROWFMA(r0.w, 12)
                ROWFMA(r1.x, 16) ROWFMA(r1.y, 20) ROWFMA(r1.z, 24) ROWFMA(r1.w, 28)
                ROWFMA(r2.x, 32) ROWFMA(r2.y, 36) ROWFMA(r2.z, 40) ROWFMA(r2.w, 44)
                ROWFMA(r3.x, 48) ROWFMA(r3.y, 52) ROWFMA(r3.z, 56) ROWFMA(r3.w, 60)
            }
        }
        // bias + relu + per-feature butterfly pool over the wave's 64 positions
#pragma unroll
        for (int k = 0; k < 64; ++k) {
            float v = valid ? fmaxf(acc[k] + bias[k], 0.f) : 0.f;
            v += __shfl_xor(v, 1);  v += __shfl_xor(v, 2);  v += __shfl_xor(v, 4);
            v += __shfl_xor(v, 8);  v += __shfl_xor(v, 16); v += __shfl_xor(v, 32);
            if (lane == k) pool += v;
        }
    }
#undef ROWFMA
    atomicAdd(&emb[g * 64 + lane], pool * (1.0f / Nn));
}

// ---- K4: gi[g][384] = emb[g] @ W_ih^T + b_ih (parallel over frames)
__global__ void k_gi(const float* __restrict__ emb, const float* __restrict__ W_ih,
                     const float* __restrict__ b_ih, float* __restrict__ gi) {
    __shared__ float xs[64];
    int g = blockIdx.x;          // g = b*Tt + t
    int j = threadIdx.x;         // 0..383
    if (j < 64) xs[j] = emb[g * 64 + j];
    __syncthreads();
    float a0 = 0.f, a1 = 0.f, a2 = 0.f, a3 = 0.f;
    const float* wr = W_ih + j * 64;
#pragma unroll
    for (int k = 0; k < 16; ++k) {
        a0 += wr[4 * k + 0] * xs[4 * k + 0];
        a1 += wr[4 * k + 1] * xs[4 * k + 1];
        a2 += wr[4 * k + 2] * xs[4 * k + 2];
        a3 += wr[4 * k + 3] * xs[4 * k + 3];
    }
    gi[(size_t)g * 384 + j] = b_ih[j] + ((a0 + a1) + (a2 + a3));
}

// ---- K5: sequential GRU over T, one block per batch, W_hh in regs + final FC
__global__ void __launch_bounds__(768, 1)
k_gru_seq(const float* __restrict__ gi, const float* __restrict__ W_hh,
          const float* __restrict__ b_hh, const float* __restrict__ fc_w,
          const float* __restrict__ fc_b, float* __restrict__ out) {
    __shared__ float h[Fg];
    __shared__ float part[768];
    int b = blockIdx.x;                  // batch
    int tid = threadIdx.x;               // 0..767
    int row = tid >> 1;                  // gate-row 0..383
    int half = tid & 1;                  // which 64-slice of k
    float w[64];
    const float* wr = W_hh + (size_t)row * Fg + half * 64;
#pragma unroll
    for (int i = 0; i < 64; ++i) w[i] = wr[i];
    if (tid < Fg) h[tid] = 0.f;
    __syncthreads();
    for (int t = 0; t < Tt; ++t) {
        const float* hh = &h[half * 64];
        float a0 = 0.f, a1 = 0.f, a2 = 0.f, a3 = 0.f;
#pragma unroll
        for (int i = 0; i < 16; ++i) {
            a0 += w[4 * i + 0] * hh[4 * i + 0];
            a1 += w[4 * i + 1] * hh[4 * i + 1];
            a2 += w[4 * i + 2] * hh[4 * i + 2];
            a3 += w[4 * i + 3] * hh[4 * i + 3];
        }
        part[tid] = (a0 + a1) + (a2 + a3);
        __syncthreads();
        if (tid < Fg) {
            int j = tid;
            const float* gib = gi + ((size_t)b * Tt + t) * 384;
            float hr = b_hh[j]       + part[2 * j]           + part[2 * j + 1];
            float hz = b_hh[128 + j] + part[2 * (128 + j)]   + part[2 * (128 + j) + 1];
            float hn = b_hh[256 + j] + part[2 * (256 + j)]   + part[2 * (256 + j) + 1];
            float r  = 1.f / (1.f + expf(-(gib[j] + hr)));
            float z  = 1.f / (1.f + expf(-(gib[128 + j] + hz)));
            float nn = tanhf(gib[256 + j] + r * hn);
            h[j] = (1.f - z) * nn + z * h[j];
        }
        __syncthreads();
    }
    if (tid < 2) {
        float acc = fc_b[tid];
        for (int k = 0; k < Fg; ++k) acc += fc_w[tid * Fg + k] * h[k];
        out[b * 2 + tid] = acc;
    }
}

// ----------------------------------------------------------------- launcher
extern "C" void kernel_launch(void* const* d_in, const int* in_sizes, int n_in,
                              void* d_out, int out_size, void* d_ws, size_t ws_size,
                              hipStream_t stream) {
    const float* x     = (const float*)d_in[0];
    const int*   ei    = (const int*)  d_in[1];
    const float* W1    = (const float*)d_in[2];
    const float* b1    = (const float*)d_in[3];
    const float* W2    = (const float*)d_in[4];
    const float* b2    = (const float*)d_in[5];
    const float* W_ih  = (const float*)d_in[6];
    const float* W_hh  = (const float*)d_in[7];
    const float* b_ih  = (const float*)d_in[8];
    const float* b_hh  = (const float*)d_in[9];
    const float* fc_w  = (const float*)d_in[10];
    const float* fc_b  = (const float*)d_in[11];
    float* out = (float*)d_out;

    char* ws = (char*)d_ws;
    size_t off = 0;
    auto alloc = [&](size_t bytes) -> void* {
        void* p = ws + off;
        off = (off + bytes + 255) & ~(size_t)255;
        return p;
    };
    float*    dis    = (float*)   alloc((size_t)G * Nn * 4);
    int*      startA = (int*)     alloc((size_t)G * Nn * 4);
    int*      cntA   = (int*)     alloc((size_t)G * Nn * 4);
    int*      cntS   = (int*)     alloc((size_t)G * Nn * 4);
    int*      ordS   = (int*)     alloc((size_t)G * Nn * 4);
    int*      csr    = (int*)     alloc((size_t)G * 4 * QCAP * 4);
    unsigned* ellT   = (unsigned*)alloc((size_t)G * TSLOT * Nn * 4);
    unsigned char* t2f = (unsigned char*)alloc((size_t)G * Nn * 64);
    float*    emb    = (float*)   alloc((size_t)G * 64 * 4);
    float*    gi     = (float*)   alloc((size_t)G * 384 * 4);
    (void)ws_size; (void)in_sizes; (void)n_in; (void)out_size;

    hipLaunchKernelGGL(k_build,   dim3(480), dim3(1024), 0, stream, ei, dis, startA, cntA, csr, ellT, cntS, ordS, emb);
    hipLaunchKernelGGL(k_fused,   dim3(960), dim3(256), 0, stream, x, ellT, cntS, ordS, startA, csr, dis, W1, b1, W2, t2f);
    hipLaunchKernelGGL(k_aggF,    dim3(240), dim3(512), 0, stream, t2f, ellT, cntS, ordS, startA, csr, dis, b2, emb);
    hipLaunchKernelGGL(k_gi,      dim3(G), dim3(384), 0, stream, emb, W_ih, b_ih, gi);
    hipLaunchKernelGGL(k_gru_seq, dim3(Bb), dim3(768), 0, stream, gi, W_hh, b_hh, fc_w, fc_b, out);
}

// Round 17
// 265.394 us; speedup vs baseline: 1.1893x; 1.0558x over previous
//
#include <hip/hip_runtime.h>
#include <math.h>

// Problem constants (fixed by the reference)
#define G    120     // B*T frames
#define Nn   2000    // nodes per frame
#define Ee   32000   // edges per frame
#define Tt   30
#define Bb   4
#define Fg   128     // GRU hidden
#define QCAP 9216    // CSR capacity per (frame,quadrant); expected 8000, sigma 78
#define TSLOT 48     // transposed-ELL slots/node: slot0=self + up to 47 edges

static __device__ __forceinline__ unsigned short f2bf(float f) {
    unsigned u = __float_as_uint(f);
    u += 0x7fffu + ((u >> 16) & 1u);          // round-to-nearest-even
    return (unsigned short)(u >> 16);
}

// ---------------- fp8 e4m3 encode/decode: HW builtins if available, SW fallback.
#if defined(__has_builtin)
#if __has_builtin(__builtin_amdgcn_cvt_f32_fp8) && __has_builtin(__builtin_amdgcn_cvt_pk_fp8_f32)
#define HW_FP8 1
#endif
#if __has_builtin(__builtin_amdgcn_cvt_pk_f32_fp8)
#define HW_FP8_PK 1
typedef float floatx2 __attribute__((ext_vector_type(2)));
#endif
#endif

static __device__ __forceinline__ unsigned fp8_enc_sw(float x) {
    unsigned s = (__float_as_uint(x) >> 24) & 0x80u;
    float ax = fminf(fabsf(x), 448.f);
    unsigned em;
    if (ax < 0.015625f) {
        em = (unsigned)__float2int_rn(ax * 512.f);
    } else {
        int e = (int)(__float_as_uint(ax) >> 23) - 127;
        float r = ax * __uint_as_float((unsigned)((130 - e) << 23));
        int q = __float2int_rn(r);
        em = (unsigned)(((e + 7) << 3) + (q - 8));
        em = min(em, 126u);
    }
    return s | em;
}
static __device__ __forceinline__ float fp8_dec_sw(unsigned b) {
    unsigned em = b & 0x7fu;
    float mag;
    if (em < 8u) mag = (float)em * 0.001953125f;
    else mag = __uint_as_float((((em >> 3) + 120u) << 23) | ((em & 7u) << 20));
    return (b & 0x80u) ? -mag : mag;
}
static __device__ __forceinline__ unsigned fp8_pack4(float a, float b, float c, float d) {
#ifdef HW_FP8
    int w = __builtin_amdgcn_cvt_pk_fp8_f32(a, b, 0, false);
    w = __builtin_amdgcn_cvt_pk_fp8_f32(c, d, w, true);
    return (unsigned)w;
#else
    return fp8_enc_sw(a) | (fp8_enc_sw(b) << 8) | (fp8_enc_sw(c) << 16) | (fp8_enc_sw(d) << 24);
#endif
}
static __device__ __forceinline__ void fp8x4_dec(unsigned dw, float* o) {
#ifdef HW_FP8_PK
    floatx2 lo = __builtin_amdgcn_cvt_pk_f32_fp8((int)dw, false);
    floatx2 hi = __builtin_amdgcn_cvt_pk_f32_fp8((int)dw, true);
    o[0] = lo[0]; o[1] = lo[1]; o[2] = hi[0]; o[3] = hi[1];
#else
    o[0] = fp8_dec_sw(dw & 0xffu);
    o[1] = fp8_dec_sw((dw >> 8) & 0xffu);
    o[2] = fp8_dec_sw((dw >> 16) & 0xffu);
    o[3] = fp8_dec_sw((dw >> 24) & 0xffu);
#endif
}

// ---- K1: fused build + per-quadrant degree counting-sort.
// Emits: dis/startA/cntA (by node, for overflow), sorted-column ellT, cntS/ordS
// (by sorted position), csr (global, only if overflow), emb zeroed.
__global__ void __launch_bounds__(1024, 1)
k_build(const int* __restrict__ ei, float* __restrict__ dis,
        int* __restrict__ startA, int* __restrict__ cntA,
        int* __restrict__ csr, unsigned* __restrict__ ellT,
        int* __restrict__ cntS, int* __restrict__ ordS,
        float* __restrict__ emb) {
    __shared__ int   hist[Nn];        // counts, then own-quadrant cursor
    __shared__ float disl[Nn];
    __shared__ int   ws[512];
    __shared__ int   csr_l[QCAP];
    __shared__ int   cntQ[500];
    __shared__ int   exQ[500];
    __shared__ int   nodeAt[500];     // sorted position -> local node idx
    __shared__ int   dh[64];          // degree histogram, then cursor
    __shared__ int   db[64];          // degree-bin exclusive base
    __shared__ int   ovfS;
    int i = blockIdx.x;               // 0..479
    int xcd = i & 7;
    int j = i >> 3;                   // 0..59
    int f15 = j >> 2;                 // 0..14
    int q = j & 3;
    int g = xcd * 15 + f15;
    int gq = g * 4 + q;
    int lo = q * 500;
    int tid = threadIdx.x;
    // P1: init
    for (int idx = tid; idx < Nn; idx += 1024) hist[idx] = 0;
    if (tid < 64) dh[tid] = 0;
    if (tid == 0) ovfS = 0;
    if (q == 0 && tid < 64) emb[g * 64 + tid] = 0.f;
    __syncthreads();
    // P2: full-frame histogram of destinations
    const int* srcp = ei + (size_t)g * 2 * Ee;
    const int* dstp = srcp + Ee;
    for (int it = tid; it < Ee / 4; it += 1024) {
        int4 d = reinterpret_cast<const int4*>(dstp)[it];
        atomicAdd(&hist[d.x], 1);
        atomicAdd(&hist[d.y], 1);
        atomicAdd(&hist[d.z], 1);
        atomicAdd(&hist[d.w], 1);
    }
    __syncthreads();
    // P3a: dis for all nodes; own-quadrant counts for scan
    for (int idx = tid; idx < Nn; idx += 1024) disl[idx] = rsqrtf((float)hist[idx] + 1.0f);
    int cnt = 0;
    if (tid < 512) ws[tid] = (tid < 500) ? hist[lo + tid] : 0;
    if (tid < 500) cnt = hist[lo + tid];
    __syncthreads();
    // P3b: inclusive scan over 512
    for (int off = 1; off < 512; off <<= 1) {
        int v = 0;
        if (tid < 512 && tid >= off) v = ws[tid - off];
        __syncthreads();
        if (tid < 512) ws[tid] += v;
        __syncthreads();
    }
    int ex = 0;
    if (tid < 500) ex = ws[tid] - cnt;
    // P3c: cursor + per-node arrays + degree histogram
    if (tid < 500) {
        hist[lo + tid] = ex;                       // cursor for P4
        cntQ[tid] = cnt;
        exQ[tid] = ex;
        if (cnt > TSLOT - 1) atomicMax(&ovfS, 1);
        atomicAdd(&dh[min(cnt, 63)], 1);
    }
    __syncthreads();
    // P3d: exclusive scan of degree bins (serial, 64 elems), then cursor=base
    if (tid == 0) {
        int s = 0;
        for (int b = 0; b < 64; ++b) { db[b] = s; s += dh[b]; }
    }
    __syncthreads();
    if (tid < 64) dh[tid] = db[tid];               // cursor per bin
    __syncthreads();
    // P3e: assign sorted positions
    if (tid < 500) {
        int p = atomicAdd(&dh[min(cnt, 63)], 1);
        nodeAt[p] = tid;
    }
    // P4: fill own-quadrant CSR in LDS
    for (int it = tid; it < Ee / 4; it += 1024) {
        int4 d = reinterpret_cast<const int4*>(dstp)[it];
        int4 s = reinterpret_cast<const int4*>(srcp)[it];
        if (d.x >= lo && d.x < lo + 500) { int p = atomicAdd(&hist[d.x], 1); if (p < QCAP) csr_l[p] = s.x; }
        if (d.y >= lo && d.y < lo + 500) { int p = atomicAdd(&hist[d.y], 1); if (p < QCAP) csr_l[p] = s.y; }
        if (d.z >= lo && d.z < lo + 500) { int p = atomicAdd(&hist[d.z], 1); if (p < QCAP) csr_l[p] = s.z; }
        if (d.w >= lo && d.w < lo + 500) { int p = atomicAdd(&hist[d.w], 1); if (p < QCAP) csr_l[p] = s.w; }
    }
    __syncthreads();
    // P5: per-node outputs. Thread t emits SORTED position t (node nodeAt[t]):
    // ELL stores coalesced across t; loop trip wave-uniform (sorted degrees).
    if (tid < 500) {
        // by-node arrays (overflow fallback + dis)
        int n_own = lo + tid;
        size_t gn_own = (size_t)g * Nn + n_own;
        cntA[gn_own] = cnt;
        startA[gn_own] = gq * QCAP + ex;
        dis[gn_own] = disl[n_own];
        // sorted emit
        int sl = nodeAt[tid];                      // local node idx at position tid
        int n2 = lo + sl;
        int cnt2 = cntQ[sl];
        int ex2 = exQ[sl];
        int c = q * 500 + tid;                     // frame-global sorted column
        size_t gc = (size_t)g * Nn + c;
        cntS[gc] = cnt2;
        ordS[gc] = n2;
        float dn2 = disl[n2];
        unsigned* et = ellT + (size_t)g * TSLOT * Nn + c;
        et[0] = (unsigned)n2 | ((unsigned)f2bf(dn2 * dn2) << 16);
        int m2 = min(cnt2, TSLOT - 1);
        for (int e = 0; e < m2; ++e) {
            int s = csr_l[ex2 + e];
            et[(size_t)(e + 1) * Nn] = (unsigned)s | ((unsigned)f2bf(disl[s] * dn2) << 16);
        }
    }
    __syncthreads();
    // P6: global CSR write only if some node overflowed (exact fallback path)
    if (ovfS) {
        int total = ws[511];
        int* cg = csr + (size_t)gq * QCAP;
        for (int it = tid; it < total; it += 1024) cg[it] = csr_l[it];
    }
}

// ---- K2: fully-fused per-lane pipeline: aggX (sorted-ELL gather of x, regs)
// -> h1 = relu(aggX@W1+b1) in regs -> t2 = h1@W2 in regs -> fp8 store by node.
// ALL array indices constant after unroll (no scratch demotion).
__global__ void __launch_bounds__(256)
k_fused(const float* __restrict__ x, const unsigned* __restrict__ ellT,
        const int* __restrict__ cntS, const int* __restrict__ ordS,
        const int* __restrict__ startA, const int* __restrict__ csr,
        const float* __restrict__ dis,
        const float* __restrict__ W1, const float* __restrict__ b1,
        const float* __restrict__ W2, unsigned char* __restrict__ t2f) {
    int i = blockIdx.x;                 // 960 = 8 xcd * 15 frames * 8 pos-blocks
    int xcd = i & 7;
    int j = i >> 3;                     // 0..119
    int g = xcd * 15 + (j >> 3);
    int blk = j & 7;
    int p = blk * 256 + threadIdx.x;    // sorted position
    bool valid = (p < Nn);
    size_t gp = (size_t)g * Nn + (valid ? p : 0);
    int n = valid ? ordS[gp] : 0;
    int cnt = valid ? cntS[gp] : 0;
    int myc = valid ? (min(cnt, TSLOT - 1) + 1) : 0;
    // phase 0: aggregate raw x (8-dim) into registers via sorted ELL
    float aX[8];
#pragma unroll
    for (int k = 0; k < 8; ++k) aX[k] = 0.f;
    {
        const unsigned* et = ellT + (size_t)g * TSLOT * Nn + (valid ? p : 0);
        const float4* x4 = reinterpret_cast<const float4*>(x + (size_t)g * Nn * 8);
        for (int e = 0; e < TSLOT; ++e) {
            if (!__any(e < myc)) break;
            if (e < myc) {
                unsigned u = et[(size_t)e * Nn];
                float w = __uint_as_float(u & 0xffff0000u);
                int s = u & 0xffffu;
                float4 r0 = x4[s * 2], r1 = x4[s * 2 + 1];
                aX[0] += r0.x * w; aX[1] += r0.y * w; aX[2] += r0.z * w; aX[3] += r0.w * w;
                aX[4] += r1.x * w; aX[5] += r1.y * w; aX[6] += r1.z * w; aX[7] += r1.w * w;
            }
        }
        if (cnt > TSLOT - 1) {          // rare overflow (deg > 47)
            size_t gn = (size_t)g * Nn + n;
            float dn = dis[gn];
            int start = startA[gn];
            const float* dsg = dis + (size_t)g * Nn;
            for (int e = TSLOT - 1; e < cnt; ++e) {
                int s = csr[start + e];
                float w = dsg[s] * dn;
                float4 r0 = x4[s * 2], r1 = x4[s * 2 + 1];
                aX[0] += r0.x * w; aX[1] += r0.y * w; aX[2] += r0.z * w; aX[3] += r0.w * w;
                aX[4] += r1.x * w; aX[5] += r1.y * w; aX[6] += r1.z * w; aX[7] += r1.w * w;
            }
        }
    }
    // phase 1: h1 = relu(aX @ W1 + b1), W1/b1 uniform scalar loads, full unroll
    float h1r[64];
    {
        const float4* b14 = reinterpret_cast<const float4*>(b1);
#pragma unroll
        for (int f4 = 0; f4 < 16; ++f4) {
            float4 b = b14[f4];
            h1r[4 * f4 + 0] = b.x; h1r[4 * f4 + 1] = b.y;
            h1r[4 * f4 + 2] = b.z; h1r[4 * f4 + 3] = b.w;
        }
        const float4* W14 = reinterpret_cast<const float4*>(W1);
#pragma unroll
        for (int k = 0; k < 8; ++k) {
            float hk = aX[k];
#pragma unroll
            for (int f4 = 0; f4 < 16; ++f4) {
                float4 w = W14[k * 16 + f4];
                h1r[4 * f4 + 0] += hk * w.x; h1r[4 * f4 + 1] += hk * w.y;
                h1r[4 * f4 + 2] += hk * w.z; h1r[4 * f4 + 3] += hk * w.w;
            }
        }
#pragma unroll
        for (int f = 0; f < 64; ++f) h1r[f] = fmaxf(h1r[f], 0.f);
    }
    // phase 2: t2 = h1 @ W2 (fp8 out), two 32-feature halves (caps live VGPRs),
    // FULL unroll everywhere -> constant indices -> no scratch.
    uint4 oh[2][2];
    {
        const float4* W24 = reinterpret_cast<const float4*>(W2);
#pragma unroll
        for (int hf = 0; hf < 2; ++hf) {
            float acch[32];
#pragma unroll
            for (int f = 0; f < 32; ++f) acch[f] = 0.f;
#pragma unroll
            for (int k = 0; k < 64; ++k) {
                float hk = h1r[k];
#pragma unroll
                for (int f4 = 0; f4 < 8; ++f4) {
                    float4 w = W24[k * 16 + hf * 8 + f4];
                    acch[4 * f4 + 0] += hk * w.x; acch[4 * f4 + 1] += hk * w.y;
                    acch[4 * f4 + 2] += hk * w.z; acch[4 * f4 + 3] += hk * w.w;
                }
            }
            oh[hf][0].x = fp8_pack4(acch[0],  acch[1],  acch[2],  acch[3]);
            oh[hf][0].y = fp8_pack4(acch[4],  acch[5],  acch[6],  acch[7]);
            oh[hf][0].z = fp8_pack4(acch[8],  acch[9],  acch[10], acch[11]);
            oh[hf][0].w = fp8_pack4(acch[12], acch[13], acch[14], acch[15]);
            oh[hf][1].x = fp8_pack4(acch[16], acch[17], acch[18], acch[19]);
            oh[hf][1].y = fp8_pack4(acch[20], acch[21], acch[22], acch[23]);
            oh[hf][1].z = fp8_pack4(acch[24], acch[25], acch[26], acch[27]);
            oh[hf][1].w = fp8_pack4(acch[28], acch[29], acch[30], acch[31]);
        }
    }
    if (valid) {
        uint4* op = reinterpret_cast<uint4*>(t2f + ((size_t)g * Nn + n) * 64);
        op[0] = oh[0][0]; op[1] = oh[0][1]; op[2] = oh[1][0]; op[3] = oh[1][1];
    }
}

// ---- K3: LDS-staged aggregation of t2 (fp8) + relu + mean-pool.
// Whole frame t2 staged once with PADDED row stride 80 B (5 uint4): b128 start
// bank = (20s+4k)%32 tiles all 32 banks -> conflict-free floor (R16's 5.19M
// SQ_LDS_BANK_CONFLICT came from the 64 B stride's 2-span aliasing).
// 1024 thr = 16 waves (4/SIMD, 2x R16's latency hiding); wave = 64 positions.
__global__ void __launch_bounds__(1024, 1)
k_aggF(const unsigned char* __restrict__ t2f, const unsigned* __restrict__ ellT,
       const int* __restrict__ cntS, const int* __restrict__ ordS,
       const int* __restrict__ startA, const int* __restrict__ csr,
       const float* __restrict__ dis, const float* __restrict__ bias,
       float* __restrict__ emb) {
    __shared__ uint4 stage[Nn * 5];     // 160,000 B; row s at stage[s*5 .. s*5+3]
    int i = blockIdx.x;                 // 240 = 8 xcd * 15 frames * 2 halves
    int xcd = i & 7;
    int j = i >> 3;                     // 0..29
    int g = xcd * 15 + (j >> 1);
    int half = j & 1;
    int tid = threadIdx.x;              // 0..1023
    int w = tid >> 6, lane = tid & 63;
    // stage entire frame t2 (fp8) into LDS with padded stride
    {
        const uint4* src = reinterpret_cast<const uint4*>(t2f + (size_t)g * Nn * 64);
        for (int it = tid; it < Nn * 4; it += 1024)
            stage[(it >> 2) * 5 + (it & 3)] = src[it];
    }
    __syncthreads();
#define ROWFMA(dw, base) { float o_[4]; fp8x4_dec(dw, o_); \
    acc[base + 0] += o_[0] * wt; acc[base + 1] += o_[1] * wt; \
    acc[base + 2] += o_[2] * wt; acc[base + 3] += o_[3] * wt; }
    int po = w * 64 + lane;             // 0..1023
    int p = half * 1000 + po;           // sorted position
    bool valid = (po < 1000);
    size_t gp = (size_t)g * Nn + (valid ? p : 0);
    int cnt = valid ? cntS[gp] : 0;
    int myc = valid ? (min(cnt, TSLOT - 1) + 1) : 0;
    float acc[64];
#pragma unroll
    for (int k = 0; k < 64; ++k) acc[k] = 0.f;
    const unsigned* et = ellT + (size_t)g * TSLOT * Nn + (valid ? p : 0);
    for (int e = 0; e < TSLOT; ++e) {
        if (!__any(e < myc)) break;
        if (e < myc) {
            unsigned u = et[(size_t)e * Nn];
            float wt = __uint_as_float(u & 0xffff0000u);
            int s = u & 0xffffu;
            uint4 r0 = stage[s * 5], r1 = stage[s * 5 + 1];
            uint4 r2 = stage[s * 5 + 2], r3 = stage[s * 5 + 3];
            ROWFMA(r0.x, 0)  ROWFMA(r0.y, 4)  ROWFMA(r0.z, 8)  ROWFMA(r0.w, 12)
            ROWFMA(r1.x, 16) ROWFMA(r1.y, 20) ROWFMA(r1.z, 24) ROWFMA(r1.w, 28)
            ROWFMA(r2.x, 32) ROWFMA(r2.y, 36) ROWFMA(r2.z, 40) ROWFMA(r2.w, 44)
            ROWFMA(r3.x, 48) ROWFMA(r3.y, 52) ROWFMA(r3.z, 56) ROWFMA(r3.w, 60)
        }
    }
    if (cnt > TSLOT - 1) {              // rare overflow (deg > 47)
        int n = ordS[gp];
        size_t gn = (size_t)g * Nn + n;
        float dn = dis[gn];
        int start = startA[gn];
        const float* dsg = dis + (size_t)g * Nn;
        for (int e = TSLOT - 1; e < cnt; ++e) {
            int s = csr[start + e];
            float wt = dsg[s] * dn;
            uint4 r0 = stage[s * 5], r1 = stage[s * 5 + 1];
            uint4 r2 = stage[s * 5 + 2], r3 = stage[s * 5 + 3];
            ROWFMA(r0.x, 0)  ROWFMA(r0.y, 4)  ROWFMA(r0.z, 8)  ROWFMA(r0.w, 12)
            ROWFMA(r1.x, 16) ROWFMA(r1.y, 20) ROWFMA(r1.z, 24) ROWFMA(r1.w, 28)
            ROWFMA(r2.x, 32) ROWFMA(r2.y, 36) ROWFMA(r2.z, 40) ROWFMA(r2.w, 44)
            ROWFMA(r3.x, 48) ROWFMA(r3.y, 52) ROWFMA(r3.z, 56) ROWFMA(r3.w, 60)
        }
    }
#undef ROWFMA
    // bias + relu + per-feature butterfly pool over the wave's 64 positions
    float pool = 0.f;
#pragma unroll
    for (int k = 0; k < 64; ++k) {
        float v = valid ? fmaxf(acc[k] + bias[k], 0.f) : 0.f;
        v += __shfl_xor(v, 1);  v += __shfl_xor(v, 2);  v += __shfl_xor(v, 4);
        v += __shfl_xor(v, 8);  v += __shfl_xor(v, 16); v += __shfl_xor(v, 32);
        if (lane == k) pool = v;
    }
    atomicAdd(&emb[g * 64 + lane], pool * (1.0f / Nn));
}

// ---- K4: gi[g][384] = emb[g] @ W_ih^T + b_ih (parallel over frames)
__global__ void k_gi(const float* __restrict__ emb, const float* __restrict__ W_ih,
                     const float* __restrict__ b_ih, float* __restrict__ gi) {
    __shared__ float xs[64];
    int g = blockIdx.x;          // g = b*Tt + t
    int j = threadIdx.x;         // 0..383
    if (j < 64) xs[j] = emb[g * 64 + j];
    __syncthreads();
    float a0 = 0.f, a1 = 0.f, a2 = 0.f, a3 = 0.f;
    const float* wr = W_ih + j * 64;
#pragma unroll
    for (int k = 0; k < 16; ++k) {
        a0 += wr[4 * k + 0] * xs[4 * k + 0];
        a1 += wr[4 * k + 1] * xs[4 * k + 1];
        a2 += wr[4 * k + 2] * xs[4 * k + 2];
        a3 += wr[4 * k + 3] * xs[4 * k + 3];
    }
    gi[(size_t)g * 384 + j] = b_ih[j] + ((a0 + a1) + (a2 + a3));
}

// ---- K5: sequential GRU over T, one block per batch, W_hh in regs + final FC
__global__ void __launch_bounds__(768, 1)
k_gru_seq(const float* __restrict__ gi, const float* __restrict__ W_hh,
          const float* __restrict__ b_hh, const float* __restrict__ fc_w,
          const float* __restrict__ fc_b, float* __restrict__ out) {
    __shared__ float h[Fg];
    __shared__ float part[768];
    int b = blockIdx.x;                  // batch
    int tid = threadIdx.x;               // 0..767
    int row = tid >> 1;                  // gate-row 0..383
    int half = tid & 1;                  // which 64-slice of k
    float w[64];
    const float* wr = W_hh + (size_t)row * Fg + half * 64;
#pragma unroll
    for (int i = 0; i < 64; ++i) w[i] = wr[i];
    if (tid < Fg) h[tid] = 0.f;
    __syncthreads();
    for (int t = 0; t < Tt; ++t) {
        const float* hh = &h[half * 64];
        float a0 = 0.f, a1 = 0.f, a2 = 0.f, a3 = 0.f;
#pragma unroll
        for (int i = 0; i < 16; ++i) {
            a0 += w[4 * i + 0] * hh[4 * i + 0];
            a1 += w[4 * i + 1] * hh[4 * i + 1];
            a2 += w[4 * i + 2] * hh[4 * i + 2];
            a3 += w[4 * i + 3] * hh[4 * i + 3];
        }
        part[tid] = (a0 + a1) + (a2 + a3);
        __syncthreads();
        if (tid < Fg) {
            int j = tid;
            const float* gib = gi + ((size_t)b * Tt + t) * 384;
            float hr = b_hh[j]       + part[2 * j]           + part[2 * j + 1];
            float hz = b_hh[128 + j] + part[2 * (128 + j)]   + part[2 * (128 + j) + 1];
            float hn = b_hh[256 + j] + part[2 * (256 + j)]   + part[2 * (256 + j) + 1];
            float r  = 1.f / (1.f + expf(-(gib[j] + hr)));
            float z  = 1.f / (1.f + expf(-(gib[128 + j] + hz)));
            float nn = tanhf(gib[256 + j] + r * hn);
            h[j] = (1.f - z) * nn + z * h[j];
        }
        __syncthreads();
    }
    if (tid < 2) {
        float acc = fc_b[tid];
        for (int k = 0; k < Fg; ++k) acc += fc_w[tid * Fg + k] * h[k];
        out[b * 2 + tid] = acc;
    }
}

// ----------------------------------------------------------------- launcher
extern "C" void kernel_launch(void* const* d_in, const int* in_sizes, int n_in,
                              void* d_out, int out_size, void* d_ws, size_t ws_size,
                              hipStream_t stream) {
    const float* x     = (const float*)d_in[0];
    const int*   ei    = (const int*)  d_in[1];
    const float* W1    = (const float*)d_in[2];
    const float* b1    = (const float*)d_in[3];
    const float* W2    = (const float*)d_in[4];
    const float* b2    = (const float*)d_in[5];
    const float* W_ih  = (const float*)d_in[6];
    const float* W_hh  = (const float*)d_in[7];
    const float* b_ih  = (const float*)d_in[8];
    const float* b_hh  = (const float*)d_in[9];
    const float* fc_w  = (const float*)d_in[10];
    const float* fc_b  = (const float*)d_in[11];
    float* out = (float*)d_out;

    char* ws = (char*)d_ws;
    size_t off = 0;
    auto alloc = [&](size_t bytes) -> void* {
        void* p = ws + off;
        off = (off + bytes + 255) & ~(size_t)255;
        return p;
    };
    float*    dis    = (float*)   alloc((size_t)G * Nn * 4);
    int*      startA = (int*)     alloc((size_t)G * Nn * 4);
    int*      cntA   = (int*)     alloc((size_t)G * Nn * 4);
    int*      cntS   = (int*)     alloc((size_t)G * Nn * 4);
    int*      ordS   = (int*)     alloc((size_t)G * Nn * 4);
    int*      csr    = (int*)     alloc((size_t)G * 4 * QCAP * 4);
    unsigned* ellT   = (unsigned*)alloc((size_t)G * TSLOT * Nn * 4);
    unsigned char* t2f = (unsigned char*)alloc((size_t)G * Nn * 64);
    float*    emb    = (float*)   alloc((size_t)G * 64 * 4);
    float*    gi     = (float*)   alloc((size_t)G * 384 * 4);
    (void)ws_size; (void)in_sizes; (void)n_in; (void)out_size;

    hipLaunchKernelGGL(k_build,   dim3(480), dim3(1024), 0, stream, ei, dis, startA, cntA, csr, ellT, cntS, ordS, emb);
    hipLaunchKernelGGL(k_fused,   dim3(960), dim3(256), 0, stream, x, ellT, cntS, ordS, startA, csr, dis, W1, b1, W2, t2f);
    hipLaunchKernelGGL(k_aggF,    dim3(240), dim3(1024), 0, stream, t2f, ellT, cntS, ordS, startA, csr, dis, b2, emb);
    hipLaunchKernelGGL(k_gi,      dim3(G), dim3(384), 0, stream, emb, W_ih, b_ih, gi);
    hipLaunchKernelGGL(k_gru_seq, dim3(Bb), dim3(768), 0, stream, gi, W_hh, b_hh, fc_w, fc_b, out);
}